// Round 4
// baseline (537.516 us; speedup 1.0000x reference)
//
#include <hip/hip_runtime.h>

// VQ: N=262144 rows, DIM=64, K=1024 codes.
// Stage 1: 32x32x16 bf16 MFMA, 3-product hi/lo split (xh.eh + xh.el + xl.eh),
//   acc init = ||e||^2 + 512 (positive scores -> raw float bits order-preserving).
//   Per-score: key = (bits & ~31) | ct ; top2 via min/max. B tiles staged to LDS
//   with global_load_lds (no VGPR round-trip), double-buffered.
// Stage 2: exact fp32 re-solve of rows flagged with margin < FLAG_EPS.
// np.argmin first-min tie-break preserved (ct in key LSBs + residue tie-break).

#define VQ_N 262144
#define VQ_DIM 64
#define VQ_K 1024
#define NT 32                  // 32 code-tiles of 32 codes
#define CHUNKS 512             // 16B chunks per tile: 256 hi + 256 lo = 8192 B
#define FLAG_EPS 1.5e-2f

typedef short short8 __attribute__((ext_vector_type(8)));
typedef float f32x16 __attribute__((ext_vector_type(16)));

// ws layout (bytes)
#define WS_BFRAG 0                   // 32 tiles * 8192 B = 262144
#define WS_E2    (256*1024)          // float[1024] raw ||e||^2 (stage2)
#define WS_FLAGS (260*1024)          // u32[8192], word w covers rows 32w..32w+31
#define WS_NEEDED (292*1024)

static __device__ __forceinline__ unsigned short f2bf_rtne(float f) {
    unsigned u = __float_as_uint(f);
    unsigned r = u + 0x7FFFu + ((u >> 16) & 1u);
    return (unsigned short)(r >> 16);
}
static __device__ __forceinline__ float bf2f(unsigned short h) {
    return __uint_as_float(((unsigned)h) << 16);
}

// ---------------- prep: B fragments (hi/lo), e2, zero flags ----------------
// chunk t = ct*512 + c;  c = arr*256 + s*64 + lane  (arr: 0=hi 1=lo)
// content: 8 bf16 of embed[ct*32 + (lane&31)][16*s + (lane>>5)*8 + j]
__global__ void vq_prep(const float* __restrict__ embed, unsigned char* __restrict__ ws) {
    int t = blockIdx.x * 256 + threadIdx.x;
    unsigned* flags = (unsigned*)(ws + WS_FLAGS);
    if (t < 8192) flags[t] = 0u;
    if (t < NT * CHUNKS) {
        int ct = t >> 9;
        int c = t & 511;
        int arr = c >> 8;
        int s = (c >> 6) & 3;
        int lane = c & 63;
        int code = ct * 32 + (lane & 31);
        int kbase = 16 * s + ((lane >> 5) << 3);
        const float* ep = embed + (size_t)code * VQ_DIM + kbase;
        short8 pack;
#pragma unroll
        for (int j = 0; j < 8; ++j) {
            float v = ep[j];
            unsigned short h = f2bf_rtne(v);
            pack[j] = arr ? (short)f2bf_rtne(v - bf2f(h)) : (short)h;
        }
        ((short8*)(ws + WS_BFRAG))[t] = pack;
    } else if (t < NT * CHUNKS + VQ_K) {
        int code = t - NT * CHUNKS;
        const float* ep = embed + (size_t)code * VQ_DIM;
        float a0 = 0, a1 = 0, a2 = 0, a3 = 0;
#pragma unroll
        for (int j = 0; j < VQ_DIM; j += 4) {
            a0 = fmaf(ep[j], ep[j], a0);
            a1 = fmaf(ep[j + 1], ep[j + 1], a1);
            a2 = fmaf(ep[j + 2], ep[j + 2], a2);
            a3 = fmaf(ep[j + 3], ep[j + 3], a3);
        }
        ((float*)(ws + WS_E2))[code] = (a0 + a1) + (a2 + a3);
    }
}

// ---------------- stage 1 ----------------
__global__ __launch_bounds__(256, 3)
void vq_stage1(const float* __restrict__ x, const float* __restrict__ embed,
               const unsigned char* __restrict__ wsro, unsigned char* __restrict__ ws,
               float* __restrict__ out) {
    __shared__ float4 lbuf[2][CHUNKS];      // 2 x 8 KB
    __shared__ float e2s[VQ_K];             // ||e||^2 + 512
    __shared__ int idx_s[4][32];

    const int tid = threadIdx.x;
    const int lane = tid & 63;
    const int wave = tid >> 6;
    const int gwave = blockIdx.x * 4 + wave;
    const int R0 = gwave * 32;
    const int row = R0 + (lane & 31);
    const int khalf = (lane >> 5) << 3;     // 0 or 8

    const short8* bsrc = (const short8*)(wsro + WS_BFRAG);
    const float* e2g = (const float*)(wsro + WS_E2);
    unsigned* flags = (unsigned*)(ws + WS_FLAGS);

    for (int c = tid; c < VQ_K; c += 256) e2s[c] = e2g[c] + 512.0f;

    // ---- A fragments: -2x, hi/lo split. Named scalars, fully unrolled (no scratch). ----
    const float* xp = x + (size_t)row * VQ_DIM + khalf;
    short8 ah0, ah1, ah2, ah3, al0, al1, al2, al3;
#define MAKE_A(S, AH, AL)                                                   \
    {                                                                       \
        const float4* p4 = (const float4*)(xp + 16 * (S));                  \
        float4 v0 = p4[0], v1 = p4[1];                                      \
        float q0 = -2.0f * v0.x, q1 = -2.0f * v0.y, q2 = -2.0f * v0.z,      \
              q3 = -2.0f * v0.w, q4 = -2.0f * v1.x, q5 = -2.0f * v1.y,      \
              q6 = -2.0f * v1.z, q7 = -2.0f * v1.w;                         \
        unsigned short h0 = f2bf_rtne(q0), h1 = f2bf_rtne(q1),              \
                       h2 = f2bf_rtne(q2), h3 = f2bf_rtne(q3),              \
                       h4 = f2bf_rtne(q4), h5 = f2bf_rtne(q5),              \
                       h6 = f2bf_rtne(q6), h7 = f2bf_rtne(q7);              \
        AH[0] = (short)h0; AH[1] = (short)h1; AH[2] = (short)h2;            \
        AH[3] = (short)h3; AH[4] = (short)h4; AH[5] = (short)h5;            \
        AH[6] = (short)h6; AH[7] = (short)h7;                               \
        AL[0] = (short)f2bf_rtne(q0 - bf2f(h0));                            \
        AL[1] = (short)f2bf_rtne(q1 - bf2f(h1));                            \
        AL[2] = (short)f2bf_rtne(q2 - bf2f(h2));                            \
        AL[3] = (short)f2bf_rtne(q3 - bf2f(h3));                            \
        AL[4] = (short)f2bf_rtne(q4 - bf2f(h4));                            \
        AL[5] = (short)f2bf_rtne(q5 - bf2f(h5));                            \
        AL[6] = (short)f2bf_rtne(q6 - bf2f(h6));                            \
        AL[7] = (short)f2bf_rtne(q7 - bf2f(h7));                            \
    }
    MAKE_A(0, ah0, al0)
    MAKE_A(1, ah1, al1)
    MAKE_A(2, ah2, al2)
    MAKE_A(3, ah3, al3)
#undef MAKE_A

    // ---- staging helper: wave stages its 128 chunks of a tile via global_load_lds ----
#define STAGE(BUF, TILE)                                                                   \
    {                                                                                      \
        const short8* g0 = bsrc + (size_t)(TILE) * CHUNKS + wave * 128 + lane;             \
        float4* l0 = &lbuf[BUF][wave * 128];                                               \
        __builtin_amdgcn_global_load_lds(                                                  \
            (const __attribute__((address_space(1))) void*)g0,                             \
            (__attribute__((address_space(3))) void*)l0, 16, 0, 0);                        \
        __builtin_amdgcn_global_load_lds(                                                  \
            (const __attribute__((address_space(1))) void*)(g0 + 64),                      \
            (__attribute__((address_space(3))) void*)(l0 + 64), 16, 0, 0);                 \
    }

    unsigned m1k[16], m2k[16];
#pragma unroll
    for (int r = 0; r < 16; ++r) { m1k[r] = 0xFFFFFFFFu; m2k[r] = 0xFFFFFFFFu; }

    STAGE(0, 0)
    __syncthreads();   // drains vmcnt(0): tile 0 resident

    for (int ct = 0; ct < NT; ++ct) {
        if (ct + 1 < NT) STAGE((ct + 1) & 1, ct + 1)

        const short8* bh = (const short8*)lbuf[ct & 1];
        const short8* bl = bh + 256;
        float e2c = e2s[ct * 32 + (lane & 31)];

        f32x16 acc = {e2c, e2c, e2c, e2c, e2c, e2c, e2c, e2c,
                      e2c, e2c, e2c, e2c, e2c, e2c, e2c, e2c};
        // xl . eh
        acc = __builtin_amdgcn_mfma_f32_32x32x16_bf16(al0, bh[0 * 64 + lane], acc, 0, 0, 0);
        acc = __builtin_amdgcn_mfma_f32_32x32x16_bf16(al1, bh[1 * 64 + lane], acc, 0, 0, 0);
        acc = __builtin_amdgcn_mfma_f32_32x32x16_bf16(al2, bh[2 * 64 + lane], acc, 0, 0, 0);
        acc = __builtin_amdgcn_mfma_f32_32x32x16_bf16(al3, bh[3 * 64 + lane], acc, 0, 0, 0);
        // xh . el
        acc = __builtin_amdgcn_mfma_f32_32x32x16_bf16(ah0, bl[0 * 64 + lane], acc, 0, 0, 0);
        acc = __builtin_amdgcn_mfma_f32_32x32x16_bf16(ah1, bl[1 * 64 + lane], acc, 0, 0, 0);
        acc = __builtin_amdgcn_mfma_f32_32x32x16_bf16(ah2, bl[2 * 64 + lane], acc, 0, 0, 0);
        acc = __builtin_amdgcn_mfma_f32_32x32x16_bf16(ah3, bl[3 * 64 + lane], acc, 0, 0, 0);
        // xh . eh
        acc = __builtin_amdgcn_mfma_f32_32x32x16_bf16(ah0, bh[0 * 64 + lane], acc, 0, 0, 0);
        acc = __builtin_amdgcn_mfma_f32_32x32x16_bf16(ah1, bh[1 * 64 + lane], acc, 0, 0, 0);
        acc = __builtin_amdgcn_mfma_f32_32x32x16_bf16(ah2, bh[2 * 64 + lane], acc, 0, 0, 0);
        acc = __builtin_amdgcn_mfma_f32_32x32x16_bf16(ah3, bh[3 * 64 + lane], acc, 0, 0, 0);

        // positive scores -> raw bits order-preserving; pack ct into low 5 bits
        unsigned ctu = (unsigned)ct;
#pragma unroll
        for (int r = 0; r < 16; ++r) {
            unsigned key = (__float_as_uint(acc[r]) & 0xFFFFFFE0u) | ctu;
            unsigned t1 = m1k[r] > key ? m1k[r] : key;
            m2k[r] = m2k[r] < t1 ? m2k[r] : t1;
            m1k[r] = m1k[r] < key ? m1k[r] : key;
        }
        __syncthreads();   // drains next-tile stage (vmcnt) + protects buffer swap
    }
#undef STAGE

    // ---- cross-lane reduce over 32 cols within each 32-lane half ----
    unsigned res[16];
#pragma unroll
    for (int r = 0; r < 16; ++r) res[r] = (unsigned)(lane & 31);
#pragma unroll
    for (int m = 1; m <= 16; m <<= 1) {
#pragma unroll
        for (int r = 0; r < 16; ++r) {
            unsigned ok = (unsigned)__shfl_xor((int)m1k[r], m);
            unsigned ok2 = (unsigned)__shfl_xor((int)m2k[r], m);
            unsigned orr = (unsigned)__shfl_xor((int)res[r], m);
            unsigned t1 = m1k[r] > ok ? m1k[r] : ok;
            unsigned c2 = ok2 < t1 ? ok2 : t1;
            m2k[r] = m2k[r] < c2 ? m2k[r] : c2;
            bool take = (ok < m1k[r]) || (ok == m1k[r] && orr < res[r]);
            if (take) { m1k[r] = ok; res[r] = orr; }
        }
    }

    // ---- lanes 0 / 32 publish idx + margin flags for their 16 rows ----
    const int h = lane >> 5;
    unsigned fmask = 0;
    if ((lane & 31) == 0) {
#pragma unroll
        for (int r = 0; r < 16; ++r) {
            int rl = (r & 3) + 8 * (r >> 2) + 4 * h;
            int code = (int)((m1k[r] & 31u) * 32u + res[r]);
            idx_s[wave][rl] = code;
            float s1 = __uint_as_float(m1k[r] & 0xFFFFFFE0u);
            float s2 = __uint_as_float(m2k[r] & 0xFFFFFFE0u);
            if (s2 - s1 < FLAG_EPS) fmask |= 1u << rl;
        }
    }
    unsigned fother = (unsigned)__shfl_xor((int)fmask, 32);
    if (lane == 0) flags[gwave] = fmask | fother;

    // ---- gather embed[idx] -> out (2 lanes per row) ----
    const int orow = lane >> 1;
    const int ohalf = lane & 1;
    int code = idx_s[wave][orow];
    const float4* ep = (const float4*)(embed + (size_t)code * VQ_DIM) + ohalf * 8;
    float4* op = (float4*)(out + (size_t)(R0 + orow) * VQ_DIM) + ohalf * 8;
#pragma unroll
    for (int j = 0; j < 8; ++j) op[j] = ep[j];
}

// ---------------- stage 2: exact fp32 re-solve of flagged rows ----------------
__global__ __launch_bounds__(256, 4)
void vq_stage2(const float* __restrict__ x, const float* __restrict__ embed,
               const unsigned char* __restrict__ ws, float* __restrict__ out) {
    const unsigned* flags = (const unsigned*)(ws + WS_FLAGS);
    const float* e2 = (const float*)(ws + WS_E2);
    int lane = threadIdx.x & 63;
    int wave = threadIdx.x >> 6;
    int w = blockIdx.x * 4 + wave;
    int rowbase = w * 64;
    unsigned fw = flags[(rowbase >> 5) + (lane >> 5)];
    int bit = (fw >> (lane & 31)) & 1;
    unsigned long long ball = __ballot(bit);
    while (ball) {
        int b = __ffsll(ball) - 1;
        ball &= ball - 1;
        int row = rowbase + b;
        const float* xr = x + (size_t)row * VQ_DIM;
        float best = __builtin_inff();
        int bi = VQ_K;
        for (int t = 0; t < VQ_K / 64; ++t) {
            int c = t * 64 + lane;
            const float* ep = embed + (size_t)c * VQ_DIM;
            float a0 = 0, a1 = 0, a2 = 0, a3 = 0;
#pragma unroll
            for (int j = 0; j < VQ_DIM; j += 4) {
                a0 = fmaf(xr[j], ep[j], a0);
                a1 = fmaf(xr[j + 1], ep[j + 1], a1);
                a2 = fmaf(xr[j + 2], ep[j + 2], a2);
                a3 = fmaf(xr[j + 3], ep[j + 3], a3);
            }
            float dot = (a0 + a1) + (a2 + a3);
            float s = fmaf(-2.0f, dot, e2[c]);
            if (s < best) { best = s; bi = c; }
        }
#pragma unroll
        for (int m = 1; m <= 32; m <<= 1) {
            float ob = __shfl_xor(best, m);
            int oi = __shfl_xor(bi, m);
            if (ob < best || (ob == best && oi < bi)) { best = ob; bi = oi; }
        }
        out[(size_t)row * VQ_DIM + lane] = embed[(size_t)bi * VQ_DIM + lane];
    }
}

// ---------------- fallback (round-1 fp32, only if ws too small) ----------------
__global__ __launch_bounds__(256, 4)
void vq_fallback(const float* __restrict__ x, const float* __restrict__ embed,
                 float* __restrict__ out) {
    __shared__ float e2s[VQ_K];
    const int tid = threadIdx.x;
    for (int c = tid; c < VQ_K; c += 256) {
        const float4* ep = (const float4*)(embed + c * VQ_DIM);
        float s = 0.0f;
#pragma unroll
        for (int j = 0; j < VQ_DIM / 4; ++j) {
            float4 v = ep[j];
            s = fmaf(v.x, v.x, s); s = fmaf(v.y, v.y, s);
            s = fmaf(v.z, v.z, s); s = fmaf(v.w, v.w, s);
        }
        e2s[c] = s;
    }
    __syncthreads();
    const int row = blockIdx.x * 256 + tid;
    float xr[VQ_DIM];
    const float4* xp = (const float4*)(x + (size_t)row * VQ_DIM);
#pragma unroll
    for (int j = 0; j < VQ_DIM / 4; ++j) {
        float4 v = xp[j];
        xr[4 * j] = v.x; xr[4 * j + 1] = v.y; xr[4 * j + 2] = v.z; xr[4 * j + 3] = v.w;
    }
    float best = __builtin_inff();
    int bidx = 0;
    for (int c = 0; c < VQ_K; ++c) {
        const float4* ep = (const float4*)(embed + c * VQ_DIM);
        float a0 = 0, a1 = 0, a2 = 0, a3 = 0;
#pragma unroll
        for (int j = 0; j < VQ_DIM / 4; ++j) {
            float4 v = ep[j];
            a0 = fmaf(xr[4 * j], v.x, a0);
            a1 = fmaf(xr[4 * j + 1], v.y, a1);
            a2 = fmaf(xr[4 * j + 2], v.z, a2);
            a3 = fmaf(xr[4 * j + 3], v.w, a3);
        }
        float score = fmaf(-2.0f, (a0 + a1) + (a2 + a3), e2s[c]);
        if (score < best) { best = score; bidx = c; }
    }
    const float4* bp = (const float4*)(embed + (size_t)bidx * VQ_DIM);
    float4* op = (float4*)(out + (size_t)row * VQ_DIM);
#pragma unroll
    for (int j = 0; j < VQ_DIM / 4; ++j) op[j] = bp[j];
}

extern "C" void kernel_launch(void* const* d_in, const int* in_sizes, int n_in,
                              void* d_out, int out_size, void* d_ws, size_t ws_size,
                              hipStream_t stream) {
    const float* x = (const float*)d_in[0];
    const float* embed = (const float*)d_in[1];
    float* out = (float*)d_out;
    if (ws_size < WS_NEEDED) {
        hipLaunchKernelGGL(vq_fallback, dim3(VQ_N / 256), dim3(256), 0, stream, x, embed, out);
        return;
    }
    unsigned char* ws = (unsigned char*)d_ws;
    hipLaunchKernelGGL(vq_prep, dim3(68), dim3(256), 0, stream, embed, ws);
    hipLaunchKernelGGL(vq_stage1, dim3(VQ_N / 128), dim3(256), 0, stream, x, embed, ws, ws, out);
    hipLaunchKernelGGL(vq_stage2, dim3(VQ_N / 256), dim3(256), 0, stream, x, embed, ws, out);
}

// Round 5
// 227.226 us; speedup vs baseline: 2.3656x; 2.3656x over previous
//
#include <hip/hip_runtime.h>

// VQ: N=262144 rows, DIM=64, K=1024 codes.
// Stage 1: 16x16x32 bf16 MFMA (R2-verified fragment layouts), 3-product hi/lo
//   split, acc init = ||e||^2 + 512 (positive scores -> raw bits order-preserving),
//   key = (bits & ~63) | ct, 4-op top2 update. 32 rows/wave as two 16-row A-sets
//   sharing one LDS B-tile read. B tiles double-buffered in LDS via plain
//   load -> ds_write (issue-early / write-late), 1 barrier per tile.
// Stage 2: exact fp32 re-solve of rows flagged with margin < FLAG_EPS.
// np.argmin first-min tie-break preserved (ct in key LSBs + residue tie-break).

#define VQ_N 262144
#define VQ_DIM 64
#define VQ_K 1024
#define NT 64                   // 64 code-tiles of 16 codes
#define TCH 256                 // 16B chunks per tile (128 hi + 128 lo) = 4096 B
#define FLAG_EPS 2.5e-2f

typedef short short8 __attribute__((ext_vector_type(8)));
typedef float f32x4 __attribute__((ext_vector_type(4)));

// ws layout (bytes)
#define WS_BFRAG 0                   // 64 tiles * 4096 B = 262144
#define WS_E2    (256*1024)          // float[1024] raw ||e||^2 (stage2)
#define WS_FLAGS (260*1024)          // u32[8192], word w covers rows 32w..32w+31
#define WS_NEEDED (292*1024)

static __device__ __forceinline__ unsigned short f2bf_rtne(float f) {
    unsigned u = __float_as_uint(f);
    unsigned r = u + 0x7FFFu + ((u >> 16) & 1u);
    return (unsigned short)(r >> 16);
}
static __device__ __forceinline__ float bf2f(unsigned short h) {
    return __uint_as_float(((unsigned)h) << 16);
}

// ---------------- prep: B fragments (hi/lo), e2, zero flags ----------------
// chunk t = ct*256 + arr*128 + kc*64 + l   (arr: 0=hi 1=lo; kc: K-chunk)
// content: 8 bf16 of embed[ct*16 + (l&15)][kc*32 + (l>>4)*8 + j]
__global__ void vq_prep(const float* __restrict__ embed, unsigned char* ws) {
    int t = blockIdx.x * 256 + threadIdx.x;     // 0 .. 17407
    unsigned* flags = (unsigned*)(ws + WS_FLAGS);
    if (t < 8192) flags[t] = 0u;
    if (t < NT * TCH) {
        int ct = t >> 8;
        int c = t & 255;
        int arr = c >> 7;
        int kc = (c >> 6) & 1;
        int l = c & 63;
        int code = ct * 16 + (l & 15);
        int kbase = kc * 32 + ((l >> 4) << 3);
        const float* ep = embed + (size_t)code * VQ_DIM + kbase;
        short8 pack;
#pragma unroll
        for (int j = 0; j < 8; ++j) {
            float v = ep[j];
            unsigned short h = f2bf_rtne(v);
            pack[j] = arr ? (short)f2bf_rtne(v - bf2f(h)) : (short)h;
        }
        ((short8*)(ws + WS_BFRAG))[t] = pack;
    } else if (t < NT * TCH + VQ_K) {
        int code = t - NT * TCH;
        const float* ep = embed + (size_t)code * VQ_DIM;
        float a0 = 0, a1 = 0, a2 = 0, a3 = 0;
#pragma unroll
        for (int j = 0; j < VQ_DIM; j += 4) {
            a0 = fmaf(ep[j], ep[j], a0);
            a1 = fmaf(ep[j + 1], ep[j + 1], a1);
            a2 = fmaf(ep[j + 2], ep[j + 2], a2);
            a3 = fmaf(ep[j + 3], ep[j + 3], a3);
        }
        ((float*)(ws + WS_E2))[code] = (a0 + a1) + (a2 + a3);
    }
}

// ---------------- stage 1 ----------------
__global__ __launch_bounds__(256, 4)
void vq_stage1(const float* __restrict__ x, const float* __restrict__ embed,
               unsigned char* ws, float* __restrict__ out) {
    __shared__ float4 lbuf[2][TCH];     // 2 x 4 KB
    __shared__ float e2s[VQ_K];         // ||e||^2 + 512
    __shared__ int idx_s[128];          // winner code per block-row

    const int tid = threadIdx.x;
    const int lane = tid & 63;
    const int wave = tid >> 6;
    const int gwave = blockIdx.x * 4 + wave;   // 0..8191, owns 32 rows
    const int R0 = gwave * 32;
    const int g = lane >> 4;            // 0..3
    const int khalf = g << 3;           // A-frag k-offset within 32-chunk

    const float4* bsrc = (const float4*)(ws + WS_BFRAG);
    const float* e2g = (const float*)(ws + WS_E2);
    unsigned* flags = (unsigned*)(ws + WS_FLAGS);

    for (int c = tid; c < VQ_K; c += 256) e2s[c] = e2g[c] + 512.0f;

    // ---- A fragments: -2x hi/lo, two 16-row sets, named scalars ----
    short8 ah00, ah01, al00, al01, ah10, ah11, al10, al11;
#define MAKE_A(ROW, KC, AH, AL)                                             \
    {                                                                       \
        const float4* p4 = (const float4*)(x + (size_t)(ROW) * VQ_DIM +     \
                                           (KC) * 32 + khalf);              \
        float4 v0 = p4[0], v1 = p4[1];                                      \
        float q0 = -2.0f * v0.x, q1 = -2.0f * v0.y, q2 = -2.0f * v0.z,      \
              q3 = -2.0f * v0.w, q4 = -2.0f * v1.x, q5 = -2.0f * v1.y,      \
              q6 = -2.0f * v1.z, q7 = -2.0f * v1.w;                         \
        unsigned short h0 = f2bf_rtne(q0), h1 = f2bf_rtne(q1),              \
                       h2 = f2bf_rtne(q2), h3 = f2bf_rtne(q3),              \
                       h4 = f2bf_rtne(q4), h5 = f2bf_rtne(q5),              \
                       h6 = f2bf_rtne(q6), h7 = f2bf_rtne(q7);              \
        AH[0] = (short)h0; AH[1] = (short)h1; AH[2] = (short)h2;            \
        AH[3] = (short)h3; AH[4] = (short)h4; AH[5] = (short)h5;            \
        AH[6] = (short)h6; AH[7] = (short)h7;                               \
        AL[0] = (short)f2bf_rtne(q0 - bf2f(h0));                            \
        AL[1] = (short)f2bf_rtne(q1 - bf2f(h1));                            \
        AL[2] = (short)f2bf_rtne(q2 - bf2f(h2));                            \
        AL[3] = (short)f2bf_rtne(q3 - bf2f(h3));                            \
        AL[4] = (short)f2bf_rtne(q4 - bf2f(h4));                            \
        AL[5] = (short)f2bf_rtne(q5 - bf2f(h5));                            \
        AL[6] = (short)f2bf_rtne(q6 - bf2f(h6));                            \
        AL[7] = (short)f2bf_rtne(q7 - bf2f(h7));                            \
    }
    const int row0 = R0 + (lane & 15);
    const int row1 = row0 + 16;
    MAKE_A(row0, 0, ah00, al00)
    MAKE_A(row0, 1, ah01, al01)
    MAKE_A(row1, 0, ah10, al10)
    MAKE_A(row1, 1, ah11, al11)
#undef MAKE_A

    unsigned m1k0[4], m2k0[4], m1k1[4], m2k1[4];
#pragma unroll
    for (int r = 0; r < 4; ++r) {
        m1k0[r] = 0xFFFFFFFFu; m2k0[r] = 0xFFFFFFFFu;
        m1k1[r] = 0xFFFFFFFFu; m2k1[r] = 0xFFFFFFFFu;
    }

    // prologue: stage tile 0 (1 chunk per thread)
    lbuf[0][tid] = bsrc[tid];
    __syncthreads();

    for (int ct = 0; ct < NT; ++ct) {
        const bool has = (ct + 1) < NT;
        float4 stv;
        if (has) stv = bsrc[(ct + 1) * TCH + tid];   // issue early

        const short8* bt = (const short8*)lbuf[ct & 1];
        short8 bh0 = bt[lane];
        short8 bh1 = bt[64 + lane];
        short8 bl0 = bt[128 + lane];
        short8 bl1 = bt[192 + lane];
        float e2c = e2s[ct * 16 + (lane & 15)];
        unsigned ctu = (unsigned)ct;

        f32x4 acc0 = {e2c, e2c, e2c, e2c};
        acc0 = __builtin_amdgcn_mfma_f32_16x16x32_bf16(al00, bh0, acc0, 0, 0, 0);
        acc0 = __builtin_amdgcn_mfma_f32_16x16x32_bf16(al01, bh1, acc0, 0, 0, 0);
        acc0 = __builtin_amdgcn_mfma_f32_16x16x32_bf16(ah00, bl0, acc0, 0, 0, 0);
        acc0 = __builtin_amdgcn_mfma_f32_16x16x32_bf16(ah01, bl1, acc0, 0, 0, 0);
        acc0 = __builtin_amdgcn_mfma_f32_16x16x32_bf16(ah00, bh0, acc0, 0, 0, 0);
        acc0 = __builtin_amdgcn_mfma_f32_16x16x32_bf16(ah01, bh1, acc0, 0, 0, 0);

        f32x4 acc1 = {e2c, e2c, e2c, e2c};
        acc1 = __builtin_amdgcn_mfma_f32_16x16x32_bf16(al10, bh0, acc1, 0, 0, 0);
        acc1 = __builtin_amdgcn_mfma_f32_16x16x32_bf16(al11, bh1, acc1, 0, 0, 0);
        acc1 = __builtin_amdgcn_mfma_f32_16x16x32_bf16(ah10, bl0, acc1, 0, 0, 0);
        acc1 = __builtin_amdgcn_mfma_f32_16x16x32_bf16(ah11, bl1, acc1, 0, 0, 0);
        acc1 = __builtin_amdgcn_mfma_f32_16x16x32_bf16(ah10, bh0, acc1, 0, 0, 0);
        acc1 = __builtin_amdgcn_mfma_f32_16x16x32_bf16(ah11, bh1, acc1, 0, 0, 0);

#pragma unroll
        for (int r = 0; r < 4; ++r) {
            unsigned key = (__float_as_uint(acc0[r]) & 0xFFFFFFC0u) | ctu;
            unsigned t1 = m1k0[r] > key ? m1k0[r] : key;
            m2k0[r] = m2k0[r] < t1 ? m2k0[r] : t1;
            m1k0[r] = m1k0[r] < key ? m1k0[r] : key;
        }
#pragma unroll
        for (int r = 0; r < 4; ++r) {
            unsigned key = (__float_as_uint(acc1[r]) & 0xFFFFFFC0u) | ctu;
            unsigned t1 = m1k1[r] > key ? m1k1[r] : key;
            m2k1[r] = m2k1[r] < t1 ? m2k1[r] : t1;
            m1k1[r] = m1k1[r] < key ? m1k1[r] : key;
        }

        if (has) lbuf[(ct + 1) & 1][tid] = stv;      // write late
        __syncthreads();
    }

    // ---- reduce over the 16 codes (lanes within each 16-group) ----
    unsigned res0[4], res1[4];
#pragma unroll
    for (int r = 0; r < 4; ++r) { res0[r] = (unsigned)(lane & 15); res1[r] = res0[r]; }
#pragma unroll
    for (int m = 1; m <= 8; m <<= 1) {
#pragma unroll
        for (int r = 0; r < 4; ++r) {
            unsigned ok = (unsigned)__shfl_xor((int)m1k0[r], m);
            unsigned ok2 = (unsigned)__shfl_xor((int)m2k0[r], m);
            unsigned orr = (unsigned)__shfl_xor((int)res0[r], m);
            unsigned t1 = m1k0[r] > ok ? m1k0[r] : ok;
            unsigned c2 = ok2 < t1 ? ok2 : t1;
            m2k0[r] = m2k0[r] < c2 ? m2k0[r] : c2;
            bool take = (ok < m1k0[r]) || (ok == m1k0[r] && orr < res0[r]);
            if (take) { m1k0[r] = ok; res0[r] = orr; }
        }
#pragma unroll
        for (int r = 0; r < 4; ++r) {
            unsigned ok = (unsigned)__shfl_xor((int)m1k1[r], m);
            unsigned ok2 = (unsigned)__shfl_xor((int)m2k1[r], m);
            unsigned orr = (unsigned)__shfl_xor((int)res1[r], m);
            unsigned t1 = m1k1[r] > ok ? m1k1[r] : ok;
            unsigned c2 = ok2 < t1 ? ok2 : t1;
            m2k1[r] = m2k1[r] < c2 ? m2k1[r] : c2;
            bool take = (ok < m1k1[r]) || (ok == m1k1[r] && orr < res1[r]);
            if (take) { m1k1[r] = ok; res1[r] = orr; }
        }
    }

    // ---- lanes 0/16/32/48 publish idx + margin flags for rows 4g+0..3 ----
    unsigned fmask = 0;
    if ((lane & 15) == 0) {
#pragma unroll
        for (int r = 0; r < 4; ++r) {
            int rl0 = 4 * g + r;            // set 0 row-in-wave
            idx_s[wave * 32 + rl0] = (int)((m1k0[r] & 63u) * 16u + res0[r]);
            float s1 = __uint_as_float(m1k0[r] & 0xFFFFFFC0u);
            float s2 = __uint_as_float(m2k0[r] & 0xFFFFFFC0u);
            if (s2 - s1 < FLAG_EPS) fmask |= 1u << rl0;
            int rl1 = 16 + 4 * g + r;       // set 1
            idx_s[wave * 32 + rl1] = (int)((m1k1[r] & 63u) * 16u + res1[r]);
            float t1f = __uint_as_float(m1k1[r] & 0xFFFFFFC0u);
            float t2f = __uint_as_float(m2k1[r] & 0xFFFFFFC0u);
            if (t2f - t1f < FLAG_EPS) fmask |= 1u << rl1;
        }
    }
    fmask |= (unsigned)__shfl_xor((int)fmask, 16);
    fmask |= (unsigned)__shfl_xor((int)fmask, 32);
    if (lane == 0) flags[gwave] = fmask;
    __syncthreads();

    // ---- gather embed[idx] -> out (2 threads per row) ----
    const int orow = tid >> 1;              // 0..127
    const int ohalf = tid & 1;
    int code = idx_s[orow];
    const float4* ep = (const float4*)(embed + (size_t)code * VQ_DIM) + ohalf * 8;
    float4* op = (float4*)(out + (size_t)(blockIdx.x * 128 + orow) * VQ_DIM) + ohalf * 8;
#pragma unroll
    for (int j = 0; j < 8; ++j) op[j] = ep[j];
}

// ---------------- stage 2: exact fp32 re-solve of flagged rows ----------------
__global__ __launch_bounds__(256, 4)
void vq_stage2(const float* __restrict__ x, const float* __restrict__ embed,
               unsigned char* ws, float* __restrict__ out) {
    const unsigned* flags = (const unsigned*)(ws + WS_FLAGS);
    const float* e2 = (const float*)(ws + WS_E2);
    int lane = threadIdx.x & 63;
    int wave = threadIdx.x >> 6;
    int w = blockIdx.x * 4 + wave;
    int rowbase = w * 64;
    unsigned fw = flags[(rowbase >> 5) + (lane >> 5)];
    int bit = (fw >> (lane & 31)) & 1;
    unsigned long long ball = __ballot(bit);
    while (ball) {
        int b = __ffsll(ball) - 1;
        ball &= ball - 1;
        int row = rowbase + b;
        const float* xr = x + (size_t)row * VQ_DIM;
        float best = __builtin_inff();
        int bi = VQ_K;
        for (int t = 0; t < VQ_K / 64; ++t) {
            int c = t * 64 + lane;
            const float* ep = embed + (size_t)c * VQ_DIM;
            float a0 = 0, a1 = 0, a2 = 0, a3 = 0;
#pragma unroll
            for (int j = 0; j < VQ_DIM; j += 4) {
                a0 = fmaf(xr[j], ep[j], a0);
                a1 = fmaf(xr[j + 1], ep[j + 1], a1);
                a2 = fmaf(xr[j + 2], ep[j + 2], a2);
                a3 = fmaf(xr[j + 3], ep[j + 3], a3);
            }
            float dot = (a0 + a1) + (a2 + a3);
            float s = fmaf(-2.0f, dot, e2[c]);
            if (s < best) { best = s; bi = c; }
        }
#pragma unroll
        for (int m = 1; m <= 32; m <<= 1) {
            float ob = __shfl_xor(best, m);
            int oi = __shfl_xor(bi, m);
            if (ob < best || (ob == best && oi < bi)) { best = ob; bi = oi; }
        }
        out[(size_t)row * VQ_DIM + lane] = embed[(size_t)bi * VQ_DIM + lane];
    }
}

// ---------------- fallback (round-1 fp32, only if ws too small) ----------------
__global__ __launch_bounds__(256, 4)
void vq_fallback(const float* __restrict__ x, const float* __restrict__ embed,
                 float* __restrict__ out) {
    __shared__ float e2s[VQ_K];
    const int tid = threadIdx.x;
    for (int c = tid; c < VQ_K; c += 256) {
        const float4* ep = (const float4*)(embed + c * VQ_DIM);
        float s = 0.0f;
#pragma unroll
        for (int j = 0; j < VQ_DIM / 4; ++j) {
            float4 v = ep[j];
            s = fmaf(v.x, v.x, s); s = fmaf(v.y, v.y, s);
            s = fmaf(v.z, v.z, s); s = fmaf(v.w, v.w, s);
        }
        e2s[c] = s;
    }
    __syncthreads();
    const int row = blockIdx.x * 256 + tid;
    float xr[VQ_DIM];
    const float4* xp = (const float4*)(x + (size_t)row * VQ_DIM);
#pragma unroll
    for (int j = 0; j < VQ_DIM / 4; ++j) {
        float4 v = xp[j];
        xr[4 * j] = v.x; xr[4 * j + 1] = v.y; xr[4 * j + 2] = v.z; xr[4 * j + 3] = v.w;
    }
    float best = __builtin_inff();
    int bidx = 0;
    for (int c = 0; c < VQ_K; ++c) {
        const float4* ep = (const float4*)(embed + c * VQ_DIM);
        float a0 = 0, a1 = 0, a2 = 0, a3 = 0;
#pragma unroll
        for (int j = 0; j < VQ_DIM / 4; ++j) {
            float4 v = ep[j];
            a0 = fmaf(xr[4 * j], v.x, a0);
            a1 = fmaf(xr[4 * j + 1], v.y, a1);
            a2 = fmaf(xr[4 * j + 2], v.z, a2);
            a3 = fmaf(xr[4 * j + 3], v.w, a3);
        }
        float score = fmaf(-2.0f, (a0 + a1) + (a2 + a3), e2s[c]);
        if (score < best) { best = score; bidx = c; }
    }
    const float4* bp = (const float4*)(embed + (size_t)bidx * VQ_DIM);
    float4* op = (float4*)(out + (size_t)row * VQ_DIM);
#pragma unroll
    for (int j = 0; j < VQ_DIM / 4; ++j) op[j] = bp[j];
}

extern "C" void kernel_launch(void* const* d_in, const int* in_sizes, int n_in,
                              void* d_out, int out_size, void* d_ws, size_t ws_size,
                              hipStream_t stream) {
    const float* x = (const float*)d_in[0];
    const float* embed = (const float*)d_in[1];
    float* out = (float*)d_out;
    if (ws_size < WS_NEEDED) {
        hipLaunchKernelGGL(vq_fallback, dim3(VQ_N / 256), dim3(256), 0, stream, x, embed, out);
        return;
    }
    unsigned char* ws = (unsigned char*)d_ws;
    hipLaunchKernelGGL(vq_prep, dim3(68), dim3(256), 0, stream, embed, ws);
    hipLaunchKernelGGL(vq_stage1, dim3(VQ_N / 128), dim3(256), 0, stream, x, embed, ws, out);
    hipLaunchKernelGGL(vq_stage2, dim3(VQ_N / 256), dim3(256), 0, stream, x, embed, ws, out);
}

// Round 6
// 198.773 us; speedup vs baseline: 2.7042x; 1.1431x over previous
//
#include <hip/hip_runtime.h>

// VQ: N=262144 rows, DIM=64, K=1024 codes.
// Stage 1: 16x16x32 bf16 MFMA, 3-product hi/lo split (xh.eh + xh.el + xl.eh),
//   acc init = ||e||^2 + 256 (positive scores < 512 -> raw bits order-preserving,
//   key mask cost <= 2e-3), key = (bits & ~63) | ct, 4-op top2 update.
//   32 rows/wave as two 16-row A-sets sharing one B read. B fragments read
//   DIRECTLY from L2 (256 KB ws stream, no LDS staging, no barriers).
// Stage 2: exact fp32 re-solve of rows flagged with margin < FLAG_EPS.
// np.argmin first-min tie-break preserved (ct in key LSBs + residue tie-break).

#define VQ_N 262144
#define VQ_DIM 64
#define VQ_K 1024
#define NT 64                   // 64 code-tiles of 16 codes
#define TCH 256                 // 16B chunks per tile (128 hi + 128 lo) = 4096 B
#define FLAG_EPS 1.2e-2f

typedef short short8 __attribute__((ext_vector_type(8)));
typedef float f32x4 __attribute__((ext_vector_type(4)));

// ws layout (bytes)
#define WS_BFRAG 0                   // 64 tiles * 4096 B = 262144
#define WS_E2    (256*1024)          // float[1024] raw ||e||^2
#define WS_FLAGS (260*1024)          // u32[8192], word w covers rows 32w..32w+31
#define WS_NEEDED (292*1024)

static __device__ __forceinline__ unsigned short f2bf_rtne(float f) {
    unsigned u = __float_as_uint(f);
    unsigned r = u + 0x7FFFu + ((u >> 16) & 1u);
    return (unsigned short)(r >> 16);
}
static __device__ __forceinline__ float bf2f(unsigned short h) {
    return __uint_as_float(((unsigned)h) << 16);
}

// ---------------- prep: B fragments (hi/lo), e2, zero flags ----------------
// chunk t = ct*256 + arr*128 + kc*64 + l   (arr: 0=hi 1=lo; kc: K-chunk)
// content: 8 bf16 of embed[ct*16 + (l&15)][kc*32 + (l>>4)*8 + j]
__global__ void vq_prep(const float* __restrict__ embed, unsigned char* ws) {
    int t = blockIdx.x * 256 + threadIdx.x;     // 0 .. 17407
    unsigned* flags = (unsigned*)(ws + WS_FLAGS);
    if (t < 8192) flags[t] = 0u;
    if (t < NT * TCH) {
        int ct = t >> 8;
        int c = t & 255;
        int arr = c >> 7;
        int kc = (c >> 6) & 1;
        int l = c & 63;
        int code = ct * 16 + (l & 15);
        int kbase = kc * 32 + ((l >> 4) << 3);
        const float* ep = embed + (size_t)code * VQ_DIM + kbase;
        short8 pack;
#pragma unroll
        for (int j = 0; j < 8; ++j) {
            float v = ep[j];
            unsigned short h = f2bf_rtne(v);
            pack[j] = arr ? (short)f2bf_rtne(v - bf2f(h)) : (short)h;
        }
        ((short8*)(ws + WS_BFRAG))[t] = pack;
    } else if (t < NT * TCH + VQ_K) {
        int code = t - NT * TCH;
        const float* ep = embed + (size_t)code * VQ_DIM;
        float a0 = 0, a1 = 0, a2 = 0, a3 = 0;
#pragma unroll
        for (int j = 0; j < VQ_DIM; j += 4) {
            a0 = fmaf(ep[j], ep[j], a0);
            a1 = fmaf(ep[j + 1], ep[j + 1], a1);
            a2 = fmaf(ep[j + 2], ep[j + 2], a2);
            a3 = fmaf(ep[j + 3], ep[j + 3], a3);
        }
        ((float*)(ws + WS_E2))[code] = (a0 + a1) + (a2 + a3);
    }
}

// ---------------- stage 1 ----------------
__global__ __launch_bounds__(256, 4)
void vq_stage1(const float* __restrict__ x, const float* __restrict__ embed,
               unsigned char* ws, float* __restrict__ out) {
    __shared__ int idx_s[128];          // winner code per block-row

    const int tid = threadIdx.x;
    const int lane = tid & 63;
    const int wave = tid >> 6;
    const int gwave = blockIdx.x * 4 + wave;   // owns 32 rows
    const int R0 = gwave * 32;
    const int g = lane >> 4;            // 0..3
    const int khalf = g << 3;           // A-frag k-offset within 32-chunk

    const short8* bsrc = (const short8*)(ws + WS_BFRAG);
    const float* e2g = (const float*)(ws + WS_E2);
    unsigned* flags = (unsigned*)(ws + WS_FLAGS);

    // ---- A fragments: -2x hi/lo, two 16-row sets, named scalars ----
    short8 ah00, ah01, al00, al01, ah10, ah11, al10, al11;
#define MAKE_A(ROW, KC, AH, AL)                                             \
    {                                                                       \
        const float4* p4 = (const float4*)(x + (size_t)(ROW) * VQ_DIM +     \
                                           (KC) * 32 + khalf);              \
        float4 v0 = p4[0], v1 = p4[1];                                      \
        float q0 = -2.0f * v0.x, q1 = -2.0f * v0.y, q2 = -2.0f * v0.z,      \
              q3 = -2.0f * v0.w, q4 = -2.0f * v1.x, q5 = -2.0f * v1.y,      \
              q6 = -2.0f * v1.z, q7 = -2.0f * v1.w;                         \
        unsigned short h0 = f2bf_rtne(q0), h1 = f2bf_rtne(q1),              \
                       h2 = f2bf_rtne(q2), h3 = f2bf_rtne(q3),              \
                       h4 = f2bf_rtne(q4), h5 = f2bf_rtne(q5),              \
                       h6 = f2bf_rtne(q6), h7 = f2bf_rtne(q7);              \
        AH[0] = (short)h0; AH[1] = (short)h1; AH[2] = (short)h2;            \
        AH[3] = (short)h3; AH[4] = (short)h4; AH[5] = (short)h5;            \
        AH[6] = (short)h6; AH[7] = (short)h7;                               \
        AL[0] = (short)f2bf_rtne(q0 - bf2f(h0));                            \
        AL[1] = (short)f2bf_rtne(q1 - bf2f(h1));                            \
        AL[2] = (short)f2bf_rtne(q2 - bf2f(h2));                            \
        AL[3] = (short)f2bf_rtne(q3 - bf2f(h3));                            \
        AL[4] = (short)f2bf_rtne(q4 - bf2f(h4));                            \
        AL[5] = (short)f2bf_rtne(q5 - bf2f(h5));                            \
        AL[6] = (short)f2bf_rtne(q6 - bf2f(h6));                            \
        AL[7] = (short)f2bf_rtne(q7 - bf2f(h7));                            \
    }
    const int row0 = R0 + (lane & 15);
    const int row1 = row0 + 16;
    MAKE_A(row0, 0, ah00, al00)
    MAKE_A(row0, 1, ah01, al01)
    MAKE_A(row1, 0, ah10, al10)
    MAKE_A(row1, 1, ah11, al11)
#undef MAKE_A

    unsigned m1k0[4], m2k0[4], m1k1[4], m2k1[4];
#pragma unroll
    for (int r = 0; r < 4; ++r) {
        m1k0[r] = 0xFFFFFFFFu; m2k0[r] = 0xFFFFFFFFu;
        m1k1[r] = 0xFFFFFFFFu; m2k1[r] = 0xFFFFFFFFu;
    }

#pragma unroll 2
    for (int ct = 0; ct < NT; ++ct) {
        const short8* bt = bsrc + (size_t)ct * TCH;
        short8 bh0 = bt[lane];
        short8 bh1 = bt[64 + lane];
        short8 bl0 = bt[128 + lane];
        short8 bl1 = bt[192 + lane];
        float e2c = e2g[ct * 16 + (lane & 15)] + 256.0f;
        unsigned ctu = (unsigned)ct;

        f32x4 acc0 = {e2c, e2c, e2c, e2c};
        acc0 = __builtin_amdgcn_mfma_f32_16x16x32_bf16(al00, bh0, acc0, 0, 0, 0);
        acc0 = __builtin_amdgcn_mfma_f32_16x16x32_bf16(al01, bh1, acc0, 0, 0, 0);
        acc0 = __builtin_amdgcn_mfma_f32_16x16x32_bf16(ah00, bl0, acc0, 0, 0, 0);
        acc0 = __builtin_amdgcn_mfma_f32_16x16x32_bf16(ah01, bl1, acc0, 0, 0, 0);
        acc0 = __builtin_amdgcn_mfma_f32_16x16x32_bf16(ah00, bh0, acc0, 0, 0, 0);
        acc0 = __builtin_amdgcn_mfma_f32_16x16x32_bf16(ah01, bh1, acc0, 0, 0, 0);

        f32x4 acc1 = {e2c, e2c, e2c, e2c};
        acc1 = __builtin_amdgcn_mfma_f32_16x16x32_bf16(al10, bh0, acc1, 0, 0, 0);
        acc1 = __builtin_amdgcn_mfma_f32_16x16x32_bf16(al11, bh1, acc1, 0, 0, 0);
        acc1 = __builtin_amdgcn_mfma_f32_16x16x32_bf16(ah10, bl0, acc1, 0, 0, 0);
        acc1 = __builtin_amdgcn_mfma_f32_16x16x32_bf16(ah11, bl1, acc1, 0, 0, 0);
        acc1 = __builtin_amdgcn_mfma_f32_16x16x32_bf16(ah10, bh0, acc1, 0, 0, 0);
        acc1 = __builtin_amdgcn_mfma_f32_16x16x32_bf16(ah11, bh1, acc1, 0, 0, 0);

#pragma unroll
        for (int r = 0; r < 4; ++r) {
            unsigned key = (__float_as_uint(acc0[r]) & 0xFFFFFFC0u) | ctu;
            unsigned t1 = m1k0[r] > key ? m1k0[r] : key;
            m2k0[r] = m2k0[r] < t1 ? m2k0[r] : t1;
            m1k0[r] = m1k0[r] < key ? m1k0[r] : key;
        }
#pragma unroll
        for (int r = 0; r < 4; ++r) {
            unsigned key = (__float_as_uint(acc1[r]) & 0xFFFFFFC0u) | ctu;
            unsigned t1 = m1k1[r] > key ? m1k1[r] : key;
            m2k1[r] = m2k1[r] < t1 ? m2k1[r] : t1;
            m1k1[r] = m1k1[r] < key ? m1k1[r] : key;
        }
    }

    // ---- reduce over the 16 codes (lanes within each 16-group) ----
    unsigned res0[4], res1[4];
#pragma unroll
    for (int r = 0; r < 4; ++r) { res0[r] = (unsigned)(lane & 15); res1[r] = res0[r]; }
#pragma unroll
    for (int m = 1; m <= 8; m <<= 1) {
#pragma unroll
        for (int r = 0; r < 4; ++r) {
            unsigned ok = (unsigned)__shfl_xor((int)m1k0[r], m);
            unsigned ok2 = (unsigned)__shfl_xor((int)m2k0[r], m);
            unsigned orr = (unsigned)__shfl_xor((int)res0[r], m);
            unsigned t1 = m1k0[r] > ok ? m1k0[r] : ok;
            unsigned c2 = ok2 < t1 ? ok2 : t1;
            m2k0[r] = m2k0[r] < c2 ? m2k0[r] : c2;
            bool take = (ok < m1k0[r]) || (ok == m1k0[r] && orr < res0[r]);
            if (take) { m1k0[r] = ok; res0[r] = orr; }
        }
#pragma unroll
        for (int r = 0; r < 4; ++r) {
            unsigned ok = (unsigned)__shfl_xor((int)m1k1[r], m);
            unsigned ok2 = (unsigned)__shfl_xor((int)m2k1[r], m);
            unsigned orr = (unsigned)__shfl_xor((int)res1[r], m);
            unsigned t1 = m1k1[r] > ok ? m1k1[r] : ok;
            unsigned c2 = ok2 < t1 ? ok2 : t1;
            m2k1[r] = m2k1[r] < c2 ? m2k1[r] : c2;
            bool take = (ok < m1k1[r]) || (ok == m1k1[r] && orr < res1[r]);
            if (take) { m1k1[r] = ok; res1[r] = orr; }
        }
    }

    // ---- lanes 0/16/32/48 publish idx + margin flags for rows 4g+0..3 ----
    unsigned fmask = 0;
    if ((lane & 15) == 0) {
#pragma unroll
        for (int r = 0; r < 4; ++r) {
            int rl0 = 4 * g + r;            // set 0 row-in-wave
            idx_s[wave * 32 + rl0] = (int)((m1k0[r] & 63u) * 16u + res0[r]);
            float s1 = __uint_as_float(m1k0[r] & 0xFFFFFFC0u);
            float s2 = __uint_as_float(m2k0[r] & 0xFFFFFFC0u);
            if (s2 - s1 < FLAG_EPS) fmask |= 1u << rl0;
            int rl1 = 16 + 4 * g + r;       // set 1
            idx_s[wave * 32 + rl1] = (int)((m1k1[r] & 63u) * 16u + res1[r]);
            float t1f = __uint_as_float(m1k1[r] & 0xFFFFFFC0u);
            float t2f = __uint_as_float(m2k1[r] & 0xFFFFFFC0u);
            if (t2f - t1f < FLAG_EPS) fmask |= 1u << rl1;
        }
    }
    fmask |= (unsigned)__shfl_xor((int)fmask, 16);
    fmask |= (unsigned)__shfl_xor((int)fmask, 32);
    if (lane == 0) flags[gwave] = fmask;
    __syncthreads();

    // ---- gather embed[idx] -> out (2 threads per row) ----
    const int orow = tid >> 1;              // 0..127
    const int ohalf = tid & 1;
    int code = idx_s[orow];
    const float4* ep = (const float4*)(embed + (size_t)code * VQ_DIM) + ohalf * 8;
    float4* op = (float4*)(out + (size_t)(blockIdx.x * 128 + orow) * VQ_DIM) + ohalf * 8;
#pragma unroll
    for (int j = 0; j < 8; ++j) op[j] = ep[j];
}

// ---------------- stage 2: exact fp32 re-solve of flagged rows ----------------
__global__ __launch_bounds__(256, 4)
void vq_stage2(const float* __restrict__ x, const float* __restrict__ embed,
               unsigned char* ws, float* __restrict__ out) {
    const unsigned* flags = (const unsigned*)(ws + WS_FLAGS);
    const float* e2 = (const float*)(ws + WS_E2);
    int lane = threadIdx.x & 63;
    int wave = threadIdx.x >> 6;
    int w = blockIdx.x * 4 + wave;
    int rowbase = w * 64;
    unsigned fw = flags[(rowbase >> 5) + (lane >> 5)];
    int bit = (fw >> (lane & 31)) & 1;
    unsigned long long ball = __ballot(bit);
    while (ball) {
        int b = __ffsll(ball) - 1;
        ball &= ball - 1;
        int row = rowbase + b;
        const float* xr = x + (size_t)row * VQ_DIM;
        float best = __builtin_inff();
        int bi = VQ_K;
        for (int t = 0; t < VQ_K / 64; ++t) {
            int c = t * 64 + lane;
            const float* ep = embed + (size_t)c * VQ_DIM;
            float a0 = 0, a1 = 0, a2 = 0, a3 = 0;
#pragma unroll
            for (int j = 0; j < VQ_DIM; j += 4) {
                a0 = fmaf(xr[j], ep[j], a0);
                a1 = fmaf(xr[j + 1], ep[j + 1], a1);
                a2 = fmaf(xr[j + 2], ep[j + 2], a2);
                a3 = fmaf(xr[j + 3], ep[j + 3], a3);
            }
            float dot = (a0 + a1) + (a2 + a3);
            float s = fmaf(-2.0f, dot, e2[c]);
            if (s < best) { best = s; bi = c; }
        }
#pragma unroll
        for (int m = 1; m <= 32; m <<= 1) {
            float ob = __shfl_xor(best, m);
            int oi = __shfl_xor(bi, m);
            if (ob < best || (ob == best && oi < bi)) { best = ob; bi = oi; }
        }
        out[(size_t)row * VQ_DIM + lane] = embed[(size_t)bi * VQ_DIM + lane];
    }
}

// ---------------- fallback (round-1 fp32, only if ws too small) ----------------
__global__ __launch_bounds__(256, 4)
void vq_fallback(const float* __restrict__ x, const float* __restrict__ embed,
                 float* __restrict__ out) {
    __shared__ float e2s[VQ_K];
    const int tid = threadIdx.x;
    for (int c = tid; c < VQ_K; c += 256) {
        const float4* ep = (const float4*)(embed + c * VQ_DIM);
        float s = 0.0f;
#pragma unroll
        for (int j = 0; j < VQ_DIM / 4; ++j) {
            float4 v = ep[j];
            s = fmaf(v.x, v.x, s); s = fmaf(v.y, v.y, s);
            s = fmaf(v.z, v.z, s); s = fmaf(v.w, v.w, s);
        }
        e2s[c] = s;
    }
    __syncthreads();
    const int row = blockIdx.x * 256 + tid;
    float xr[VQ_DIM];
    const float4* xp = (const float4*)(x + (size_t)row * VQ_DIM);
#pragma unroll
    for (int j = 0; j < VQ_DIM / 4; ++j) {
        float4 v = xp[j];
        xr[4 * j] = v.x; xr[4 * j + 1] = v.y; xr[4 * j + 2] = v.z; xr[4 * j + 3] = v.w;
    }
    float best = __builtin_inff();
    int bidx = 0;
    for (int c = 0; c < VQ_K; ++c) {
        const float4* ep = (const float4*)(embed + c * VQ_DIM);
        float a0 = 0, a1 = 0, a2 = 0, a3 = 0;
#pragma unroll
        for (int j = 0; j < VQ_DIM / 4; ++j) {
            float4 v = ep[j];
            a0 = fmaf(xr[4 * j], v.x, a0);
            a1 = fmaf(xr[4 * j + 1], v.y, a1);
            a2 = fmaf(xr[4 * j + 2], v.z, a2);
            a3 = fmaf(xr[4 * j + 3], v.w, a3);
        }
        float score = fmaf(-2.0f, (a0 + a1) + (a2 + a3), e2s[c]);
        if (score < best) { best = score; bidx = c; }
    }
    const float4* bp = (const float4*)(embed + (size_t)bidx * VQ_DIM);
    float4* op = (float4*)(out + (size_t)row * VQ_DIM);
#pragma unroll
    for (int j = 0; j < VQ_DIM / 4; ++j) op[j] = bp[j];
}

extern "C" void kernel_launch(void* const* d_in, const int* in_sizes, int n_in,
                              void* d_out, int out_size, void* d_ws, size_t ws_size,
                              hipStream_t stream) {
    const float* x = (const float*)d_in[0];
    const float* embed = (const float*)d_in[1];
    float* out = (float*)d_out;
    if (ws_size < WS_NEEDED) {
        hipLaunchKernelGGL(vq_fallback, dim3(VQ_N / 256), dim3(256), 0, stream, x, embed, out);
        return;
    }
    unsigned char* ws = (unsigned char*)d_ws;
    hipLaunchKernelGGL(vq_prep, dim3(68), dim3(256), 0, stream, embed, ws);
    hipLaunchKernelGGL(vq_stage1, dim3(VQ_N / 128), dim3(256), 0, stream, x, embed, ws, out);
    hipLaunchKernelGGL(vq_stage2, dim3(VQ_N / 256), dim3(256), 0, stream, x, embed, ws, out);
}

// Round 7
// 183.263 us; speedup vs baseline: 2.9330x; 1.0846x over previous
//
#include <hip/hip_runtime.h>

// VQ: N=262144 rows, DIM=64, K=1024 codes.
// Stage 1 (single kernel): 16x16x32 bf16 MFMA, 3-product hi/lo split
//   (xh.eh + xh.el + xl.eh), acc init = ||e||^2 + 256 (positive scores ->
//   raw float bits order-preserving), key = (bits & ~63) | ct, 4-op top2.
//   64 rows/wave = four 16-row A-sets sharing each B-tile read (B from L2).
//   Rows with top2 margin < FLAG_EPS are exactly re-solved IN-WAVE (fp32).
// np.argmin first-min tie-break preserved (ct in key LSBs + residue tie-break;
//   near-ties are flagged and re-solved exactly).

#define VQ_N 262144
#define VQ_DIM 64
#define VQ_K 1024
#define NT 64                   // 64 code-tiles of 16 codes
#define TCH 256                 // 16B chunks per tile (128 hi + 128 lo) = 4096 B
#define FLAG_EPS 1.2e-2f

typedef short short8 __attribute__((ext_vector_type(8)));
typedef float f32x4 __attribute__((ext_vector_type(4)));

// ws layout (bytes)
#define WS_BFRAG 0                   // 64 tiles * 4096 B = 262144
#define WS_E2    (256*1024)          // float[1024] raw ||e||^2
#define WS_NEEDED (260*1024)

static __device__ __forceinline__ unsigned short f2bf_rtne(float f) {
    unsigned u = __float_as_uint(f);
    unsigned r = u + 0x7FFFu + ((u >> 16) & 1u);
    return (unsigned short)(r >> 16);
}
static __device__ __forceinline__ float bf2f(unsigned short h) {
    return __uint_as_float(((unsigned)h) << 16);
}

// ---------------- prep: B fragments (hi/lo), e2 ----------------
// chunk t = ct*256 + arr*128 + kc*64 + l   (arr: 0=hi 1=lo; kc: K-chunk)
// content: 8 bf16 of embed[ct*16 + (l&15)][kc*32 + (l>>4)*8 + j]
__global__ void vq_prep(const float* __restrict__ embed, unsigned char* ws) {
    int t = blockIdx.x * 256 + threadIdx.x;     // 0 .. 17407
    if (t < NT * TCH) {
        int ct = t >> 8;
        int c = t & 255;
        int arr = c >> 7;
        int kc = (c >> 6) & 1;
        int l = c & 63;
        int code = ct * 16 + (l & 15);
        int kbase = kc * 32 + ((l >> 4) << 3);
        const float* ep = embed + (size_t)code * VQ_DIM + kbase;
        short8 pack;
#pragma unroll
        for (int j = 0; j < 8; ++j) {
            float v = ep[j];
            unsigned short h = f2bf_rtne(v);
            pack[j] = arr ? (short)f2bf_rtne(v - bf2f(h)) : (short)h;
        }
        ((short8*)(ws + WS_BFRAG))[t] = pack;
    } else if (t < NT * TCH + VQ_K) {
        int code = t - NT * TCH;
        const float* ep = embed + (size_t)code * VQ_DIM;
        float a0 = 0, a1 = 0, a2 = 0, a3 = 0;
#pragma unroll
        for (int j = 0; j < VQ_DIM; j += 4) {
            a0 = fmaf(ep[j], ep[j], a0);
            a1 = fmaf(ep[j + 1], ep[j + 1], a1);
            a2 = fmaf(ep[j + 2], ep[j + 2], a2);
            a3 = fmaf(ep[j + 3], ep[j + 3], a3);
        }
        ((float*)(ws + WS_E2))[code] = (a0 + a1) + (a2 + a3);
    }
}

// ---------------- stage 1: scan + gather + in-wave exact re-solve ----------------
__global__ __launch_bounds__(256, 2)
void vq_stage1(const float* __restrict__ x, const float* __restrict__ embed,
               unsigned char* ws, float* __restrict__ out) {
    __shared__ int idx_s[4][64];        // winner code per wave-row

    const int tid = threadIdx.x;
    const int lane = tid & 63;
    const int wave = tid >> 6;
    const int gwave = blockIdx.x * 4 + wave;   // owns 64 rows
    const int R0 = gwave * 64;
    const int g = lane >> 4;            // 0..3
    const int khalf = g << 3;           // A-frag k-offset within 32-chunk

    const short8* bsrc = (const short8*)(ws + WS_BFRAG);
    const float* e2g = (const float*)(ws + WS_E2);

    // ---- A fragments: -2x hi/lo, four 16-row sets, named scalars ----
    short8 ah00, ah01, al00, al01, ah10, ah11, al10, al11;
    short8 ah20, ah21, al20, al21, ah30, ah31, al30, al31;
#define MAKE_A(ROW, KC, AH, AL)                                             \
    {                                                                       \
        const float4* p4 = (const float4*)(x + (size_t)(ROW) * VQ_DIM +     \
                                           (KC) * 32 + khalf);              \
        float4 v0 = p4[0], v1 = p4[1];                                      \
        float q0 = -2.0f * v0.x, q1 = -2.0f * v0.y, q2 = -2.0f * v0.z,      \
              q3 = -2.0f * v0.w, q4 = -2.0f * v1.x, q5 = -2.0f * v1.y,      \
              q6 = -2.0f * v1.z, q7 = -2.0f * v1.w;                         \
        unsigned short h0 = f2bf_rtne(q0), h1 = f2bf_rtne(q1),              \
                       h2 = f2bf_rtne(q2), h3 = f2bf_rtne(q3),              \
                       h4 = f2bf_rtne(q4), h5 = f2bf_rtne(q5),              \
                       h6 = f2bf_rtne(q6), h7 = f2bf_rtne(q7);              \
        AH[0] = (short)h0; AH[1] = (short)h1; AH[2] = (short)h2;            \
        AH[3] = (short)h3; AH[4] = (short)h4; AH[5] = (short)h5;            \
        AH[6] = (short)h6; AH[7] = (short)h7;                               \
        AL[0] = (short)f2bf_rtne(q0 - bf2f(h0));                            \
        AL[1] = (short)f2bf_rtne(q1 - bf2f(h1));                            \
        AL[2] = (short)f2bf_rtne(q2 - bf2f(h2));                            \
        AL[3] = (short)f2bf_rtne(q3 - bf2f(h3));                            \
        AL[4] = (short)f2bf_rtne(q4 - bf2f(h4));                            \
        AL[5] = (short)f2bf_rtne(q5 - bf2f(h5));                            \
        AL[6] = (short)f2bf_rtne(q6 - bf2f(h6));                            \
        AL[7] = (short)f2bf_rtne(q7 - bf2f(h7));                            \
    }
    const int rowb = R0 + (lane & 15);
    MAKE_A(rowb +  0, 0, ah00, al00)  MAKE_A(rowb +  0, 1, ah01, al01)
    MAKE_A(rowb + 16, 0, ah10, al10)  MAKE_A(rowb + 16, 1, ah11, al11)
    MAKE_A(rowb + 32, 0, ah20, al20)  MAKE_A(rowb + 32, 1, ah21, al21)
    MAKE_A(rowb + 48, 0, ah30, al30)  MAKE_A(rowb + 48, 1, ah31, al31)
#undef MAKE_A

    unsigned m1k0[4], m2k0[4], m1k1[4], m2k1[4];
    unsigned m1k2[4], m2k2[4], m1k3[4], m2k3[4];
#pragma unroll
    for (int r = 0; r < 4; ++r) {
        m1k0[r] = 0xFFFFFFFFu; m2k0[r] = 0xFFFFFFFFu;
        m1k1[r] = 0xFFFFFFFFu; m2k1[r] = 0xFFFFFFFFu;
        m1k2[r] = 0xFFFFFFFFu; m2k2[r] = 0xFFFFFFFFu;
        m1k3[r] = 0xFFFFFFFFu; m2k3[r] = 0xFFFFFFFFu;
    }

#define DO_SET(AH0, AH1, AL0, AL1, M1, M2)                                            \
    {                                                                                 \
        f32x4 acc = {e2c, e2c, e2c, e2c};                                             \
        acc = __builtin_amdgcn_mfma_f32_16x16x32_bf16(AL0, bh0, acc, 0, 0, 0);        \
        acc = __builtin_amdgcn_mfma_f32_16x16x32_bf16(AL1, bh1, acc, 0, 0, 0);        \
        acc = __builtin_amdgcn_mfma_f32_16x16x32_bf16(AH0, bl0, acc, 0, 0, 0);        \
        acc = __builtin_amdgcn_mfma_f32_16x16x32_bf16(AH1, bl1, acc, 0, 0, 0);        \
        acc = __builtin_amdgcn_mfma_f32_16x16x32_bf16(AH0, bh0, acc, 0, 0, 0);        \
        acc = __builtin_amdgcn_mfma_f32_16x16x32_bf16(AH1, bh1, acc, 0, 0, 0);        \
        _Pragma("unroll")                                                             \
        for (int r = 0; r < 4; ++r) {                                                 \
            unsigned key = (__float_as_uint(acc[r]) & 0xFFFFFFC0u) | ctu;             \
            unsigned t1 = M1[r] > key ? M1[r] : key;                                  \
            M2[r] = M2[r] < t1 ? M2[r] : t1;                                          \
            M1[r] = M1[r] < key ? M1[r] : key;                                        \
        }                                                                             \
    }

#pragma unroll 2
    for (int ct = 0; ct < NT; ++ct) {
        const short8* bt = bsrc + (size_t)ct * TCH;
        short8 bh0 = bt[lane];
        short8 bh1 = bt[64 + lane];
        short8 bl0 = bt[128 + lane];
        short8 bl1 = bt[192 + lane];
        float e2c = e2g[ct * 16 + (lane & 15)] + 256.0f;
        unsigned ctu = (unsigned)ct;

        DO_SET(ah00, ah01, al00, al01, m1k0, m2k0)
        DO_SET(ah10, ah11, al10, al11, m1k1, m2k1)
        DO_SET(ah20, ah21, al20, al21, m1k2, m2k2)
        DO_SET(ah30, ah31, al30, al31, m1k3, m2k3)
    }
#undef DO_SET

    // ---- reduce over the 16 codes (lanes within each 16-group) ----
    unsigned res0[4], res1[4], res2[4], res3[4];
#pragma unroll
    for (int r = 0; r < 4; ++r) {
        res0[r] = (unsigned)(lane & 15); res1[r] = res0[r];
        res2[r] = res0[r]; res3[r] = res0[r];
    }
#define RED_STEP(M1, M2, RES, m)                                                      \
    {                                                                                 \
        _Pragma("unroll")                                                             \
        for (int r = 0; r < 4; ++r) {                                                 \
            unsigned ok = (unsigned)__shfl_xor((int)M1[r], m);                        \
            unsigned ok2 = (unsigned)__shfl_xor((int)M2[r], m);                       \
            unsigned orr = (unsigned)__shfl_xor((int)RES[r], m);                      \
            unsigned t1 = M1[r] > ok ? M1[r] : ok;                                    \
            unsigned c2 = ok2 < t1 ? ok2 : t1;                                        \
            M2[r] = M2[r] < c2 ? M2[r] : c2;                                          \
            bool take = (ok < M1[r]) || (ok == M1[r] && orr < RES[r]);                \
            if (take) { M1[r] = ok; RES[r] = orr; }                                   \
        }                                                                             \
    }
#pragma unroll
    for (int m = 1; m <= 8; m <<= 1) {
        RED_STEP(m1k0, m2k0, res0, m)
        RED_STEP(m1k1, m2k1, res1, m)
        RED_STEP(m1k2, m2k2, res2, m)
        RED_STEP(m1k3, m2k3, res3, m)
    }
#undef RED_STEP

    // ---- lanes 0/16/32/48 publish idx + build wave-local 64-bit flag mask ----
    unsigned long long lmask = 0ull;
    if ((lane & 15) == 0) {
#define PUB(M1, M2, RES, SET)                                                         \
        _Pragma("unroll")                                                             \
        for (int r = 0; r < 4; ++r) {                                                 \
            int p = (SET) * 16 + 4 * g + r;                                           \
            idx_s[wave][p] = (int)((M1[r] & 63u) * 16u + RES[r]);                     \
            float s1 = __uint_as_float(M1[r] & 0xFFFFFFC0u);                          \
            float s2 = __uint_as_float(M2[r] & 0xFFFFFFC0u);                          \
            if (s2 - s1 < FLAG_EPS) lmask |= 1ull << p;                               \
        }
        PUB(m1k0, m2k0, res0, 0)
        PUB(m1k1, m2k1, res1, 1)
        PUB(m1k2, m2k2, res2, 2)
        PUB(m1k3, m2k3, res3, 3)
#undef PUB
    }
    lmask |= (unsigned long long)__shfl_xor((long long)lmask, 16);
    lmask |= (unsigned long long)__shfl_xor((long long)lmask, 32);
    unsigned long long wmask = (unsigned long long)__shfl((long long)lmask, 0);
    __syncthreads();

    // ---- gather embed[idx] -> out (coalesced: 16 threads span one row) ----
    const int chunk = tid & 15;
#pragma unroll
    for (int jj = 0; jj < 16; ++jj) {
        int rib = jj * 16 + (tid >> 4);           // row in block 0..255
        int code = idx_s[rib >> 6][rib & 63];
        const float4* ep = (const float4*)(embed + (size_t)code * VQ_DIM) + chunk;
        float4* op = (float4*)(out + (size_t)(blockIdx.x * 256 + rib) * VQ_DIM) + chunk;
        *op = *ep;
    }
    __syncthreads();

    // ---- in-wave exact fp32 re-solve of flagged rows (rare) ----
    while (wmask) {
        int b = __ffsll((unsigned long long)wmask) - 1;
        wmask &= wmask - 1;
        int row = R0 + b;
        const float* xr = x + (size_t)row * VQ_DIM;
        float xv[VQ_DIM];
#pragma unroll
        for (int j = 0; j < VQ_DIM / 4; ++j) {
            float4 v = ((const float4*)xr)[j];
            xv[4 * j] = v.x; xv[4 * j + 1] = v.y;
            xv[4 * j + 2] = v.z; xv[4 * j + 3] = v.w;
        }
        float best = __builtin_inff();
        int bi = VQ_K;
        for (int t = 0; t < VQ_K / 64; ++t) {
            int c = t * 64 + lane;
            const float* ep = embed + (size_t)c * VQ_DIM;
            float a0 = 0, a1 = 0, a2 = 0, a3 = 0;
#pragma unroll
            for (int j = 0; j < VQ_DIM; j += 4) {
                a0 = fmaf(xv[j], ep[j], a0);
                a1 = fmaf(xv[j + 1], ep[j + 1], a1);
                a2 = fmaf(xv[j + 2], ep[j + 2], a2);
                a3 = fmaf(xv[j + 3], ep[j + 3], a3);
            }
            float dot = (a0 + a1) + (a2 + a3);
            float s = fmaf(-2.0f, dot, e2g[c]);
            if (s < best || (s == best && c < bi)) { best = s; bi = c; }
        }
#pragma unroll
        for (int m = 1; m <= 32; m <<= 1) {
            float ob = __shfl_xor(best, m);
            int oi = __shfl_xor(bi, m);
            if (ob < best || (ob == best && oi < bi)) { best = ob; bi = oi; }
        }
        out[(size_t)row * VQ_DIM + lane] = embed[(size_t)bi * VQ_DIM + lane];
    }
}

// ---------------- fallback (round-1 fp32, only if ws too small) ----------------
__global__ __launch_bounds__(256, 4)
void vq_fallback(const float* __restrict__ x, const float* __restrict__ embed,
                 float* __restrict__ out) {
    __shared__ float e2s[VQ_K];
    const int tid = threadIdx.x;
    for (int c = tid; c < VQ_K; c += 256) {
        const float4* ep = (const float4*)(embed + c * VQ_DIM);
        float s = 0.0f;
#pragma unroll
        for (int j = 0; j < VQ_DIM / 4; ++j) {
            float4 v = ep[j];
            s = fmaf(v.x, v.x, s); s = fmaf(v.y, v.y, s);
            s = fmaf(v.z, v.z, s); s = fmaf(v.w, v.w, s);
        }
        e2s[c] = s;
    }
    __syncthreads();
    const int row = blockIdx.x * 256 + tid;
    float xr[VQ_DIM];
    const float4* xp = (const float4*)(x + (size_t)row * VQ_DIM);
#pragma unroll
    for (int j = 0; j < VQ_DIM / 4; ++j) {
        float4 v = xp[j];
        xr[4 * j] = v.x; xr[4 * j + 1] = v.y; xr[4 * j + 2] = v.z; xr[4 * j + 3] = v.w;
    }
    float best = __builtin_inff();
    int bidx = 0;
    for (int c = 0; c < VQ_K; ++c) {
        const float4* ep = (const float4*)(embed + c * VQ_DIM);
        float a0 = 0, a1 = 0, a2 = 0, a3 = 0;
#pragma unroll
        for (int j = 0; j < VQ_DIM / 4; ++j) {
            float4 v = ep[j];
            a0 = fmaf(xr[4 * j], v.x, a0);
            a1 = fmaf(xr[4 * j + 1], v.y, a1);
            a2 = fmaf(xr[4 * j + 2], v.z, a2);
            a3 = fmaf(xr[4 * j + 3], v.w, a3);
        }
        float score = fmaf(-2.0f, (a0 + a1) + (a2 + a3), e2s[c]);
        if (score < best) { best = score; bidx = c; }
    }
    const float4* bp = (const float4*)(embed + (size_t)bidx * VQ_DIM);
    float4* op = (float4*)(out + (size_t)row * VQ_DIM);
#pragma unroll
    for (int j = 0; j < VQ_DIM / 4; ++j) op[j] = bp[j];
}

extern "C" void kernel_launch(void* const* d_in, const int* in_sizes, int n_in,
                              void* d_out, int out_size, void* d_ws, size_t ws_size,
                              hipStream_t stream) {
    const float* x = (const float*)d_in[0];
    const float* embed = (const float*)d_in[1];
    float* out = (float*)d_out;
    if (ws_size < WS_NEEDED) {
        hipLaunchKernelGGL(vq_fallback, dim3(VQ_N / 256), dim3(256), 0, stream, x, embed, out);
        return;
    }
    unsigned char* ws = (unsigned char*)d_ws;
    hipLaunchKernelGGL(vq_prep, dim3(68), dim3(256), 0, stream, embed, ws);
    hipLaunchKernelGGL(vq_stage1, dim3(VQ_N / 256), dim3(256), 0, stream, x, embed, ws, out);
}

// Round 8
// 172.790 us; speedup vs baseline: 3.1108x; 1.0606x over previous
//
#include <hip/hip_runtime.h>

// VQ: N=262144 rows, DIM=64, K=1024 codes.
// Single compute kernel: 16x16x32 bf16 MFMA, 3-product hi/lo split
//   (xh.eh + xh.el + xl.eh), acc init = ||e||^2 + 256 (positive scores ->
//   raw float bits order-preserving), key = (bits & ~63) | ct, 4-op top2.
//   32 rows/wave (two 16-row A-sets share each B read). B tiles read from L2
//   with an explicit 2-tile register pipeline + per-wave rotated tile order.
//   Rows with top2 margin < FLAG_EPS are exactly re-solved IN-WAVE (fp32).
// np.argmin first-min tie-break preserved (ct in key LSBs + residue tie-break;
//   near-ties re-solved exactly with index-ordered selection).

#define VQ_N 262144
#define VQ_DIM 64
#define VQ_K 1024
#define NT 64                   // 64 code-tiles of 16 codes
#define TCH 256                 // 16B chunks per tile (128 hi + 128 lo) = 4096 B
#define FLAG_EPS 1.2e-2f

typedef short short8 __attribute__((ext_vector_type(8)));
typedef float f32x4 __attribute__((ext_vector_type(4)));

// ws layout (bytes)
#define WS_BFRAG 0                   // 64 tiles * 4096 B = 262144
#define WS_E2    (256*1024)          // float[1024] raw ||e||^2 (exact resolve)
#define WS_E2P   (260*1024)          // float[1024] ||e||^2 + 256 (scan init)
#define WS_NEEDED (264*1024)

static __device__ __forceinline__ unsigned short f2bf_rtne(float f) {
    unsigned u = __float_as_uint(f);
    unsigned r = u + 0x7FFFu + ((u >> 16) & 1u);
    return (unsigned short)(r >> 16);
}
static __device__ __forceinline__ float bf2f(unsigned short h) {
    return __uint_as_float(((unsigned)h) << 16);
}

// ---------------- prep: B fragments (hi/lo), e2 / e2+256 ----------------
// chunk t = ct*256 + arr*128 + kc*64 + l   (arr: 0=hi 1=lo; kc: K-chunk)
// content: 8 bf16 of embed[ct*16 + (l&15)][kc*32 + (l>>4)*8 + j]
__global__ void vq_prep(const float* __restrict__ embed, unsigned char* ws) {
    int t = blockIdx.x * 256 + threadIdx.x;     // 0 .. 17407
    if (t < NT * TCH) {
        int ct = t >> 8;
        int c = t & 255;
        int arr = c >> 7;
        int kc = (c >> 6) & 1;
        int l = c & 63;
        int code = ct * 16 + (l & 15);
        int kbase = kc * 32 + ((l >> 4) << 3);
        const float* ep = embed + (size_t)code * VQ_DIM + kbase;
        short8 pack;
#pragma unroll
        for (int j = 0; j < 8; ++j) {
            float v = ep[j];
            unsigned short h = f2bf_rtne(v);
            pack[j] = arr ? (short)f2bf_rtne(v - bf2f(h)) : (short)h;
        }
        ((short8*)(ws + WS_BFRAG))[t] = pack;
    } else if (t < NT * TCH + VQ_K) {
        int code = t - NT * TCH;
        const float* ep = embed + (size_t)code * VQ_DIM;
        float a0 = 0, a1 = 0, a2 = 0, a3 = 0;
#pragma unroll
        for (int j = 0; j < VQ_DIM; j += 4) {
            a0 = fmaf(ep[j], ep[j], a0);
            a1 = fmaf(ep[j + 1], ep[j + 1], a1);
            a2 = fmaf(ep[j + 2], ep[j + 2], a2);
            a3 = fmaf(ep[j + 3], ep[j + 3], a3);
        }
        float e2 = (a0 + a1) + (a2 + a3);
        ((float*)(ws + WS_E2))[code] = e2;
        ((float*)(ws + WS_E2P))[code] = e2 + 256.0f;
    }
}

// ---------------- stage 1: scan + gather + in-wave exact re-solve ----------------
__global__ __launch_bounds__(256, 4)
void vq_stage1(const float* __restrict__ x, const float* __restrict__ embed,
               unsigned char* ws, float* __restrict__ out) {
    __shared__ int idx_s[4][32];        // winner code per wave-row

    const int tid = threadIdx.x;
    const int lane = tid & 63;
    const int wave = tid >> 6;
    const int gwave = blockIdx.x * 4 + wave;   // owns 32 rows
    const int R0 = gwave * 32;
    const int g = lane >> 4;            // 0..3
    const int khalf = g << 3;           // A-frag k-offset within 32-chunk

    const short8* bsrc = (const short8*)(ws + WS_BFRAG);
    const float* e2g = (const float*)(ws + WS_E2);
    const float* e2p = (const float*)(ws + WS_E2P);

    // ---- A fragments: -2x hi/lo, two 16-row sets, named scalars ----
    short8 ah00, ah01, al00, al01, ah10, ah11, al10, al11;
#define MAKE_A(ROW, KC, AH, AL)                                             \
    {                                                                       \
        const float4* p4 = (const float4*)(x + (size_t)(ROW) * VQ_DIM +     \
                                           (KC) * 32 + khalf);              \
        float4 v0 = p4[0], v1 = p4[1];                                      \
        float q0 = -2.0f * v0.x, q1 = -2.0f * v0.y, q2 = -2.0f * v0.z,      \
              q3 = -2.0f * v0.w, q4 = -2.0f * v1.x, q5 = -2.0f * v1.y,      \
              q6 = -2.0f * v1.z, q7 = -2.0f * v1.w;                         \
        unsigned short h0 = f2bf_rtne(q0), h1 = f2bf_rtne(q1),              \
                       h2 = f2bf_rtne(q2), h3 = f2bf_rtne(q3),              \
                       h4 = f2bf_rtne(q4), h5 = f2bf_rtne(q5),              \
                       h6 = f2bf_rtne(q6), h7 = f2bf_rtne(q7);              \
        AH[0] = (short)h0; AH[1] = (short)h1; AH[2] = (short)h2;            \
        AH[3] = (short)h3; AH[4] = (short)h4; AH[5] = (short)h5;            \
        AH[6] = (short)h6; AH[7] = (short)h7;                               \
        AL[0] = (short)f2bf_rtne(q0 - bf2f(h0));                            \
        AL[1] = (short)f2bf_rtne(q1 - bf2f(h1));                            \
        AL[2] = (short)f2bf_rtne(q2 - bf2f(h2));                            \
        AL[3] = (short)f2bf_rtne(q3 - bf2f(h3));                            \
        AL[4] = (short)f2bf_rtne(q4 - bf2f(h4));                            \
        AL[5] = (short)f2bf_rtne(q5 - bf2f(h5));                            \
        AL[6] = (short)f2bf_rtne(q6 - bf2f(h6));                            \
        AL[7] = (short)f2bf_rtne(q7 - bf2f(h7));                            \
    }
    const int row0 = R0 + (lane & 15);
    const int row1 = row0 + 16;
    MAKE_A(row0, 0, ah00, al00)
    MAKE_A(row0, 1, ah01, al01)
    MAKE_A(row1, 0, ah10, al10)
    MAKE_A(row1, 1, ah11, al11)
#undef MAKE_A

    unsigned m1k0[4], m2k0[4], m1k1[4], m2k1[4];
#pragma unroll
    for (int r = 0; r < 4; ++r) {
        m1k0[r] = 0xFFFFFFFFu; m2k0[r] = 0xFFFFFFFFu;
        m1k1[r] = 0xFFFFFFFFu; m2k1[r] = 0xFFFFFFFFu;
    }

#define LOAD_B(CT, B0, B1, B2, B3)                                          \
    {                                                                       \
        const short8* bt = bsrc + (size_t)(CT) * TCH;                       \
        B0 = bt[lane]; B1 = bt[64 + lane];                                  \
        B2 = bt[128 + lane]; B3 = bt[192 + lane];                           \
    }

#define DO_SET(AH0, AH1, AL0, AL1, B0, B1, B2, B3, M1, M2)                            \
    {                                                                                 \
        f32x4 acc = {e2c, e2c, e2c, e2c};                                             \
        acc = __builtin_amdgcn_mfma_f32_16x16x32_bf16(AL0, B0, acc, 0, 0, 0);         \
        acc = __builtin_amdgcn_mfma_f32_16x16x32_bf16(AL1, B1, acc, 0, 0, 0);         \
        acc = __builtin_amdgcn_mfma_f32_16x16x32_bf16(AH0, B2, acc, 0, 0, 0);         \
        acc = __builtin_amdgcn_mfma_f32_16x16x32_bf16(AH1, B3, acc, 0, 0, 0);         \
        acc = __builtin_amdgcn_mfma_f32_16x16x32_bf16(AH0, B0, acc, 0, 0, 0);         \
        acc = __builtin_amdgcn_mfma_f32_16x16x32_bf16(AH1, B1, acc, 0, 0, 0);         \
        _Pragma("unroll")                                                             \
        for (int r = 0; r < 4; ++r) {                                                 \
            unsigned key = (__float_as_uint(acc[r]) & 0xFFFFFFC0u) | ctu;             \
            unsigned t1 = M1[r] > key ? M1[r] : key;                                  \
            M2[r] = M2[r] < t1 ? M2[r] : t1;                                          \
            M1[r] = M1[r] < key ? M1[r] : key;                                        \
        }                                                                             \
    }

#define DO_TILE(CT, B0, B1, B2, B3)                                                   \
    {                                                                                 \
        float e2c = e2p[(CT) * 16 + (lane & 15)];                                     \
        unsigned ctu = (unsigned)(CT);                                                \
        DO_SET(ah00, ah01, al00, al01, B0, B1, B2, B3, m1k0, m2k0)                    \
        DO_SET(ah10, ah11, al10, al11, B0, B1, B2, B3, m1k1, m2k1)                    \
    }

    // ---- main scan: 2-tile register pipeline, per-wave rotated order ----
    const int rot = gwave & 63;
    short8 pb0, pb1, pb2, pb3, qb0, qb1, qb2, qb3;
    LOAD_B(rot, pb0, pb1, pb2, pb3)
    for (int it = 0; it < NT; it += 2) {
        const int cte = (rot + it) & 63;
        const int cto = (rot + it + 1) & 63;
        const int ctn = (rot + it + 2) & 63;      // wraps to rot at the end: harmless
        LOAD_B(cto, qb0, qb1, qb2, qb3)           // prefetch odd tile
        DO_TILE(cte, pb0, pb1, pb2, pb3)          // compute even tile
        LOAD_B(ctn, pb0, pb1, pb2, pb3)           // prefetch next even tile
        DO_TILE(cto, qb0, qb1, qb2, qb3)          // compute odd tile
    }
#undef DO_TILE
#undef DO_SET
#undef LOAD_B

    // ---- reduce over the 16 codes (lanes within each 16-group) ----
    unsigned res0[4], res1[4];
#pragma unroll
    for (int r = 0; r < 4; ++r) { res0[r] = (unsigned)(lane & 15); res1[r] = res0[r]; }
#define RED_STEP(M1, M2, RES, m)                                                      \
    {                                                                                 \
        _Pragma("unroll")                                                             \
        for (int r = 0; r < 4; ++r) {                                                 \
            unsigned ok = (unsigned)__shfl_xor((int)M1[r], m);                        \
            unsigned ok2 = (unsigned)__shfl_xor((int)M2[r], m);                       \
            unsigned orr = (unsigned)__shfl_xor((int)RES[r], m);                      \
            unsigned t1 = M1[r] > ok ? M1[r] : ok;                                    \
            unsigned c2 = ok2 < t1 ? ok2 : t1;                                        \
            M2[r] = M2[r] < c2 ? M2[r] : c2;                                          \
            bool take = (ok < M1[r]) || (ok == M1[r] && orr < RES[r]);                \
            if (take) { M1[r] = ok; RES[r] = orr; }                                   \
        }                                                                             \
    }
#pragma unroll
    for (int m = 1; m <= 8; m <<= 1) {
        RED_STEP(m1k0, m2k0, res0, m)
        RED_STEP(m1k1, m2k1, res1, m)
    }
#undef RED_STEP

    // ---- lanes 0/16/32/48 publish idx + build wave 32-bit flag mask ----
    unsigned fmask = 0;
    if ((lane & 15) == 0) {
#pragma unroll
        for (int r = 0; r < 4; ++r) {
            int rl0 = 4 * g + r;
            idx_s[wave][rl0] = (int)((m1k0[r] & 63u) * 16u + res0[r]);
            float s1 = __uint_as_float(m1k0[r] & 0xFFFFFFC0u);
            float s2 = __uint_as_float(m2k0[r] & 0xFFFFFFC0u);
            if (s2 - s1 < FLAG_EPS) fmask |= 1u << rl0;
            int rl1 = 16 + 4 * g + r;
            idx_s[wave][rl1] = (int)((m1k1[r] & 63u) * 16u + res1[r]);
            float t1f = __uint_as_float(m1k1[r] & 0xFFFFFFC0u);
            float t2f = __uint_as_float(m2k1[r] & 0xFFFFFFC0u);
            if (t2f - t1f < FLAG_EPS) fmask |= 1u << rl1;
        }
    }
    fmask |= (unsigned)__shfl_xor((int)fmask, 16);
    fmask |= (unsigned)__shfl_xor((int)fmask, 32);
    unsigned wmask = (unsigned)__shfl((int)fmask, 0);
    __syncthreads();

    // ---- gather embed[idx] -> out (2 threads per row) ----
    const int orow = tid >> 1;              // 0..127
    const int ohalf = tid & 1;
    int code = idx_s[orow >> 5][orow & 31];
    const float4* ep = (const float4*)(embed + (size_t)code * VQ_DIM) + ohalf * 8;
    float4* op = (float4*)(out + (size_t)(blockIdx.x * 128 + orow) * VQ_DIM) + ohalf * 8;
#pragma unroll
    for (int j = 0; j < 8; ++j) op[j] = ep[j];
    __syncthreads();

    // ---- in-wave exact fp32 re-solve of flagged rows (rare) ----
    while (wmask) {
        int b = __ffs(wmask) - 1;
        wmask &= wmask - 1;
        int row = R0 + b;
        const float* xr = x + (size_t)row * VQ_DIM;
        float xv[VQ_DIM];
#pragma unroll
        for (int j = 0; j < VQ_DIM / 4; ++j) {
            float4 v = ((const float4*)xr)[j];
            xv[4 * j] = v.x; xv[4 * j + 1] = v.y;
            xv[4 * j + 2] = v.z; xv[4 * j + 3] = v.w;
        }
        float best = __builtin_inff();
        int bi = VQ_K;
        for (int t = 0; t < VQ_K / 64; ++t) {
            int c = t * 64 + lane;
            const float* ep2 = embed + (size_t)c * VQ_DIM;
            float a0 = 0, a1 = 0, a2 = 0, a3 = 0;
#pragma unroll
            for (int j = 0; j < VQ_DIM; j += 4) {
                a0 = fmaf(xv[j], ep2[j], a0);
                a1 = fmaf(xv[j + 1], ep2[j + 1], a1);
                a2 = fmaf(xv[j + 2], ep2[j + 2], a2);
                a3 = fmaf(xv[j + 3], ep2[j + 3], a3);
            }
            float dot = (a0 + a1) + (a2 + a3);
            float s = fmaf(-2.0f, dot, e2g[c]);
            if (s < best || (s == best && c < bi)) { best = s; bi = c; }
        }
#pragma unroll
        for (int m = 1; m <= 32; m <<= 1) {
            float ob = __shfl_xor(best, m);
            int oi = __shfl_xor(bi, m);
            if (ob < best || (ob == best && oi < bi)) { best = ob; bi = oi; }
        }
        out[(size_t)row * VQ_DIM + lane] = embed[(size_t)bi * VQ_DIM + lane];
    }
}

// ---------------- fallback (round-1 fp32, only if ws too small) ----------------
__global__ __launch_bounds__(256, 4)
void vq_fallback(const float* __restrict__ x, const float* __restrict__ embed,
                 float* __restrict__ out) {
    __shared__ float e2s[VQ_K];
    const int tid = threadIdx.x;
    for (int c = tid; c < VQ_K; c += 256) {
        const float4* ep = (const float4*)(embed + c * VQ_DIM);
        float s = 0.0f;
#pragma unroll
        for (int j = 0; j < VQ_DIM / 4; ++j) {
            float4 v = ep[j];
            s = fmaf(v.x, v.x, s); s = fmaf(v.y, v.y, s);
            s = fmaf(v.z, v.z, s); s = fmaf(v.w, v.w, s);
        }
        e2s[c] = s;
    }
    __syncthreads();
    const int row = blockIdx.x * 256 + tid;
    float xr[VQ_DIM];
    const float4* xp = (const float4*)(x + (size_t)row * VQ_DIM);
#pragma unroll
    for (int j = 0; j < VQ_DIM / 4; ++j) {
        float4 v = xp[j];
        xr[4 * j] = v.x; xr[4 * j + 1] = v.y; xr[4 * j + 2] = v.z; xr[4 * j + 3] = v.w;
    }
    float best = __builtin_inff();
    int bidx = 0;
    for (int c = 0; c < VQ_K; ++c) {
        const float4* ep = (const float4*)(embed + c * VQ_DIM);
        float a0 = 0, a1 = 0, a2 = 0, a3 = 0;
#pragma unroll
        for (int j = 0; j < VQ_DIM / 4; ++j) {
            float4 v = ep[j];
            a0 = fmaf(xr[4 * j], v.x, a0);
            a1 = fmaf(xr[4 * j + 1], v.y, a1);
            a2 = fmaf(xr[4 * j + 2], v.z, a2);
            a3 = fmaf(xr[4 * j + 3], v.w, a3);
        }
        float score = fmaf(-2.0f, (a0 + a1) + (a2 + a3), e2s[c]);
        if (score < best) { best = score; bidx = c; }
    }
    const float4* bp = (const float4*)(embed + (size_t)bidx * VQ_DIM);
    float4* op = (float4*)(out + (size_t)row * VQ_DIM);
#pragma unroll
    for (int j = 0; j < VQ_DIM / 4; ++j) op[j] = bp[j];
}

extern "C" void kernel_launch(void* const* d_in, const int* in_sizes, int n_in,
                              void* d_out, int out_size, void* d_ws, size_t ws_size,
                              hipStream_t stream) {
    const float* x = (const float*)d_in[0];
    const float* embed = (const float*)d_in[1];
    float* out = (float*)d_out;
    if (ws_size < WS_NEEDED) {
        hipLaunchKernelGGL(vq_fallback, dim3(VQ_N / 256), dim3(256), 0, stream, x, embed, out);
        return;
    }
    unsigned char* ws = (unsigned char*)d_ws;
    hipLaunchKernelGGL(vq_prep, dim3(68), dim3(256), 0, stream, embed, ws);
    hipLaunchKernelGGL(vq_stage1, dim3(VQ_N / 128), dim3(256), 0, stream, x, embed, ws, out);
}

// Round 9
// 172.294 us; speedup vs baseline: 3.1198x; 1.0029x over previous
//
#include <hip/hip_runtime.h>

// VQ: N=262144 rows, DIM=64, K=1024 codes.
// Single compute kernel (R6 scan + in-wave exact resolve):
//   16x16x32 bf16 MFMA, 3-product hi/lo split (xh.eh + xh.el + xl.eh),
//   acc init = ||e||^2 + 256 (positive scores -> raw bits order-preserving),
//   key = (bits & ~63) | ct, 4-op top2. 32 rows/wave, two 16-row A-sets share
//   each B read; B tiles read directly from L2, sequential order (waves in a
//   block share the tile stream -> L2 broadcast), compiler unroll-2 prefetch.
//   Rows with top2 margin < FLAG_EPS are exactly re-solved IN-WAVE (fp32).
// np.argmin first-min tie-break preserved (ct in key LSBs + residue tie-break;
//   near-ties re-solved exactly with index-ordered selection).

#define VQ_N 262144
#define VQ_DIM 64
#define VQ_K 1024
#define NT 64                   // 64 code-tiles of 16 codes
#define TCH 256                 // 16B chunks per tile (128 hi + 128 lo) = 4096 B
#define FLAG_EPS 1.2e-2f

typedef short short8 __attribute__((ext_vector_type(8)));
typedef float f32x4 __attribute__((ext_vector_type(4)));

// ws layout (bytes)
#define WS_BFRAG 0                   // 64 tiles * 4096 B = 262144
#define WS_E2    (256*1024)          // float[1024] raw ||e||^2
#define WS_NEEDED (260*1024)

static __device__ __forceinline__ unsigned short f2bf_rtne(float f) {
    unsigned u = __float_as_uint(f);
    unsigned r = u + 0x7FFFu + ((u >> 16) & 1u);
    return (unsigned short)(r >> 16);
}
static __device__ __forceinline__ float bf2f(unsigned short h) {
    return __uint_as_float(((unsigned)h) << 16);
}

// ---------------- prep: B fragments (hi/lo), e2 ----------------
// chunk t = ct*256 + arr*128 + kc*64 + l   (arr: 0=hi 1=lo; kc: K-chunk)
// content: 8 bf16 of embed[ct*16 + (l&15)][kc*32 + (l>>4)*8 + j]
__global__ void vq_prep(const float* __restrict__ embed, unsigned char* ws) {
    int t = blockIdx.x * 256 + threadIdx.x;     // 0 .. 17407
    if (t < NT * TCH) {
        int ct = t >> 8;
        int c = t & 255;
        int arr = c >> 7;
        int kc = (c >> 6) & 1;
        int l = c & 63;
        int code = ct * 16 + (l & 15);
        int kbase = kc * 32 + ((l >> 4) << 3);
        const float* ep = embed + (size_t)code * VQ_DIM + kbase;
        short8 pack;
#pragma unroll
        for (int j = 0; j < 8; ++j) {
            float v = ep[j];
            unsigned short h = f2bf_rtne(v);
            pack[j] = arr ? (short)f2bf_rtne(v - bf2f(h)) : (short)h;
        }
        ((short8*)(ws + WS_BFRAG))[t] = pack;
    } else if (t < NT * TCH + VQ_K) {
        int code = t - NT * TCH;
        const float* ep = embed + (size_t)code * VQ_DIM;
        float a0 = 0, a1 = 0, a2 = 0, a3 = 0;
#pragma unroll
        for (int j = 0; j < VQ_DIM; j += 4) {
            a0 = fmaf(ep[j], ep[j], a0);
            a1 = fmaf(ep[j + 1], ep[j + 1], a1);
            a2 = fmaf(ep[j + 2], ep[j + 2], a2);
            a3 = fmaf(ep[j + 3], ep[j + 3], a3);
        }
        ((float*)(ws + WS_E2))[code] = (a0 + a1) + (a2 + a3);
    }
}

// ---------------- stage 1: scan + gather + in-wave exact re-solve ----------------
__global__ __launch_bounds__(256, 4)
void vq_stage1(const float* __restrict__ x, const float* __restrict__ embed,
               unsigned char* ws, float* __restrict__ out) {
    __shared__ int idx_s[4][32];        // winner code per wave-row

    const int tid = threadIdx.x;
    const int lane = tid & 63;
    const int wave = tid >> 6;
    const int gwave = blockIdx.x * 4 + wave;   // owns 32 rows
    const int R0 = gwave * 32;
    const int g = lane >> 4;            // 0..3
    const int khalf = g << 3;           // A-frag k-offset within 32-chunk

    const short8* bsrc = (const short8*)(ws + WS_BFRAG);
    const float* e2g = (const float*)(ws + WS_E2);

    // ---- A fragments: -2x hi/lo, two 16-row sets, named scalars ----
    short8 ah00, ah01, al00, al01, ah10, ah11, al10, al11;
#define MAKE_A(ROW, KC, AH, AL)                                             \
    {                                                                       \
        const float4* p4 = (const float4*)(x + (size_t)(ROW) * VQ_DIM +     \
                                           (KC) * 32 + khalf);              \
        float4 v0 = p4[0], v1 = p4[1];                                      \
        float q0 = -2.0f * v0.x, q1 = -2.0f * v0.y, q2 = -2.0f * v0.z,      \
              q3 = -2.0f * v0.w, q4 = -2.0f * v1.x, q5 = -2.0f * v1.y,      \
              q6 = -2.0f * v1.z, q7 = -2.0f * v1.w;                         \
        unsigned short h0 = f2bf_rtne(q0), h1 = f2bf_rtne(q1),              \
                       h2 = f2bf_rtne(q2), h3 = f2bf_rtne(q3),              \
                       h4 = f2bf_rtne(q4), h5 = f2bf_rtne(q5),              \
                       h6 = f2bf_rtne(q6), h7 = f2bf_rtne(q7);              \
        AH[0] = (short)h0; AH[1] = (short)h1; AH[2] = (short)h2;            \
        AH[3] = (short)h3; AH[4] = (short)h4; AH[5] = (short)h5;            \
        AH[6] = (short)h6; AH[7] = (short)h7;                               \
        AL[0] = (short)f2bf_rtne(q0 - bf2f(h0));                            \
        AL[1] = (short)f2bf_rtne(q1 - bf2f(h1));                            \
        AL[2] = (short)f2bf_rtne(q2 - bf2f(h2));                            \
        AL[3] = (short)f2bf_rtne(q3 - bf2f(h3));                            \
        AL[4] = (short)f2bf_rtne(q4 - bf2f(h4));                            \
        AL[5] = (short)f2bf_rtne(q5 - bf2f(h5));                            \
        AL[6] = (short)f2bf_rtne(q6 - bf2f(h6));                            \
        AL[7] = (short)f2bf_rtne(q7 - bf2f(h7));                            \
    }
    const int row0 = R0 + (lane & 15);
    const int row1 = row0 + 16;
    MAKE_A(row0, 0, ah00, al00)
    MAKE_A(row0, 1, ah01, al01)
    MAKE_A(row1, 0, ah10, al10)
    MAKE_A(row1, 1, ah11, al11)
#undef MAKE_A

    unsigned m1k0[4], m2k0[4], m1k1[4], m2k1[4];
#pragma unroll
    for (int r = 0; r < 4; ++r) {
        m1k0[r] = 0xFFFFFFFFu; m2k0[r] = 0xFFFFFFFFu;
        m1k1[r] = 0xFFFFFFFFu; m2k1[r] = 0xFFFFFFFFu;
    }

    // ---- main scan (R6 structure: sequential tiles, compiler prefetch) ----
#pragma unroll 2
    for (int ct = 0; ct < NT; ++ct) {
        const short8* bt = bsrc + (size_t)ct * TCH;
        short8 bh0 = bt[lane];
        short8 bh1 = bt[64 + lane];
        short8 bl0 = bt[128 + lane];
        short8 bl1 = bt[192 + lane];
        float e2c = e2g[ct * 16 + (lane & 15)] + 256.0f;
        unsigned ctu = (unsigned)ct;

        f32x4 acc0 = {e2c, e2c, e2c, e2c};
        acc0 = __builtin_amdgcn_mfma_f32_16x16x32_bf16(al00, bh0, acc0, 0, 0, 0);
        acc0 = __builtin_amdgcn_mfma_f32_16x16x32_bf16(al01, bh1, acc0, 0, 0, 0);
        acc0 = __builtin_amdgcn_mfma_f32_16x16x32_bf16(ah00, bl0, acc0, 0, 0, 0);
        acc0 = __builtin_amdgcn_mfma_f32_16x16x32_bf16(ah01, bl1, acc0, 0, 0, 0);
        acc0 = __builtin_amdgcn_mfma_f32_16x16x32_bf16(ah00, bh0, acc0, 0, 0, 0);
        acc0 = __builtin_amdgcn_mfma_f32_16x16x32_bf16(ah01, bh1, acc0, 0, 0, 0);

        f32x4 acc1 = {e2c, e2c, e2c, e2c};
        acc1 = __builtin_amdgcn_mfma_f32_16x16x32_bf16(al10, bh0, acc1, 0, 0, 0);
        acc1 = __builtin_amdgcn_mfma_f32_16x16x32_bf16(al11, bh1, acc1, 0, 0, 0);
        acc1 = __builtin_amdgcn_mfma_f32_16x16x32_bf16(ah10, bl0, acc1, 0, 0, 0);
        acc1 = __builtin_amdgcn_mfma_f32_16x16x32_bf16(ah11, bl1, acc1, 0, 0, 0);
        acc1 = __builtin_amdgcn_mfma_f32_16x16x32_bf16(ah10, bh0, acc1, 0, 0, 0);
        acc1 = __builtin_amdgcn_mfma_f32_16x16x32_bf16(ah11, bh1, acc1, 0, 0, 0);

#pragma unroll
        for (int r = 0; r < 4; ++r) {
            unsigned key = (__float_as_uint(acc0[r]) & 0xFFFFFFC0u) | ctu;
            unsigned t1 = m1k0[r] > key ? m1k0[r] : key;
            m2k0[r] = m2k0[r] < t1 ? m2k0[r] : t1;
            m1k0[r] = m1k0[r] < key ? m1k0[r] : key;
        }
#pragma unroll
        for (int r = 0; r < 4; ++r) {
            unsigned key = (__float_as_uint(acc1[r]) & 0xFFFFFFC0u) | ctu;
            unsigned t1 = m1k1[r] > key ? m1k1[r] : key;
            m2k1[r] = m2k1[r] < t1 ? m2k1[r] : t1;
            m1k1[r] = m1k1[r] < key ? m1k1[r] : key;
        }
    }

    // ---- reduce over the 16 codes (lanes within each 16-group) ----
    unsigned res0[4], res1[4];
#pragma unroll
    for (int r = 0; r < 4; ++r) { res0[r] = (unsigned)(lane & 15); res1[r] = res0[r]; }
#define RED_STEP(M1, M2, RES, m)                                                      \
    {                                                                                 \
        _Pragma("unroll")                                                             \
        for (int r = 0; r < 4; ++r) {                                                 \
            unsigned ok = (unsigned)__shfl_xor((int)M1[r], m);                        \
            unsigned ok2 = (unsigned)__shfl_xor((int)M2[r], m);                       \
            unsigned orr = (unsigned)__shfl_xor((int)RES[r], m);                      \
            unsigned t1 = M1[r] > ok ? M1[r] : ok;                                    \
            unsigned c2 = ok2 < t1 ? ok2 : t1;                                        \
            M2[r] = M2[r] < c2 ? M2[r] : c2;                                          \
            bool take = (ok < M1[r]) || (ok == M1[r] && orr < RES[r]);                \
            if (take) { M1[r] = ok; RES[r] = orr; }                                   \
        }                                                                             \
    }
#pragma unroll
    for (int m = 1; m <= 8; m <<= 1) {
        RED_STEP(m1k0, m2k0, res0, m)
        RED_STEP(m1k1, m2k1, res1, m)
    }
#undef RED_STEP

    // ---- lanes 0/16/32/48 publish idx + build wave 32-bit flag mask ----
    unsigned fmask = 0;
    if ((lane & 15) == 0) {
#pragma unroll
        for (int r = 0; r < 4; ++r) {
            int rl0 = 4 * g + r;
            idx_s[wave][rl0] = (int)((m1k0[r] & 63u) * 16u + res0[r]);
            float s1 = __uint_as_float(m1k0[r] & 0xFFFFFFC0u);
            float s2 = __uint_as_float(m2k0[r] & 0xFFFFFFC0u);
            if (s2 - s1 < FLAG_EPS) fmask |= 1u << rl0;
            int rl1 = 16 + 4 * g + r;
            idx_s[wave][rl1] = (int)((m1k1[r] & 63u) * 16u + res1[r]);
            float t1f = __uint_as_float(m1k1[r] & 0xFFFFFFC0u);
            float t2f = __uint_as_float(m2k1[r] & 0xFFFFFFC0u);
            if (t2f - t1f < FLAG_EPS) fmask |= 1u << rl1;
        }
    }
    fmask |= (unsigned)__shfl_xor((int)fmask, 16);
    fmask |= (unsigned)__shfl_xor((int)fmask, 32);
    unsigned wmask = (unsigned)__shfl((int)fmask, 0);
    __syncthreads();

    // ---- gather embed[idx] -> out (2 threads per row) ----
    const int orow = tid >> 1;              // 0..127
    const int ohalf = tid & 1;
    int code = idx_s[orow >> 5][orow & 31];
    const float4* ep = (const float4*)(embed + (size_t)code * VQ_DIM) + ohalf * 8;
    float4* op = (float4*)(out + (size_t)(blockIdx.x * 128 + orow) * VQ_DIM) + ohalf * 8;
#pragma unroll
    for (int j = 0; j < 8; ++j) op[j] = ep[j];

    // ---- in-wave exact fp32 re-solve of flagged rows (rare) ----
    while (wmask) {
        int b = __ffs(wmask) - 1;
        wmask &= wmask - 1;
        int row = R0 + b;
        const float* xr = x + (size_t)row * VQ_DIM;
        float xv[VQ_DIM];
#pragma unroll
        for (int j = 0; j < VQ_DIM / 4; ++j) {
            float4 v = ((const float4*)xr)[j];
            xv[4 * j] = v.x; xv[4 * j + 1] = v.y;
            xv[4 * j + 2] = v.z; xv[4 * j + 3] = v.w;
        }
        float best = __builtin_inff();
        int bi = VQ_K;
        for (int t = 0; t < VQ_K / 64; ++t) {
            int c = t * 64 + lane;
            const float* ep2 = embed + (size_t)c * VQ_DIM;
            float a0 = 0, a1 = 0, a2 = 0, a3 = 0;
#pragma unroll
            for (int j = 0; j < VQ_DIM; j += 4) {
                a0 = fmaf(xv[j], ep2[j], a0);
                a1 = fmaf(xv[j + 1], ep2[j + 1], a1);
                a2 = fmaf(xv[j + 2], ep2[j + 2], a2);
                a3 = fmaf(xv[j + 3], ep2[j + 3], a3);
            }
            float dot = (a0 + a1) + (a2 + a3);
            float s = fmaf(-2.0f, dot, e2g[c]);
            if (s < best || (s == best && c < bi)) { best = s; bi = c; }
        }
#pragma unroll
        for (int m = 1; m <= 32; m <<= 1) {
            float ob = __shfl_xor(best, m);
            int oi = __shfl_xor(bi, m);
            if (ob < best || (ob == best && oi < bi)) { best = ob; bi = oi; }
        }
        out[(size_t)row * VQ_DIM + lane] = embed[(size_t)bi * VQ_DIM + lane];
    }
}

// ---------------- fallback (round-1 fp32, only if ws too small) ----------------
__global__ __launch_bounds__(256, 4)
void vq_fallback(const float* __restrict__ x, const float* __restrict__ embed,
                 float* __restrict__ out) {
    __shared__ float e2s[VQ_K];
    const int tid = threadIdx.x;
    for (int c = tid; c < VQ_K; c += 256) {
        const float4* ep = (const float4*)(embed + c * VQ_DIM);
        float s = 0.0f;
#pragma unroll
        for (int j = 0; j < VQ_DIM / 4; ++j) {
            float4 v = ep[j];
            s = fmaf(v.x, v.x, s); s = fmaf(v.y, v.y, s);
            s = fmaf(v.z, v.z, s); s = fmaf(v.w, v.w, s);
        }
        e2s[c] = s;
    }
    __syncthreads();
    const int row = blockIdx.x * 256 + tid;
    float xr[VQ_DIM];
    const float4* xp = (const float4*)(x + (size_t)row * VQ_DIM);
#pragma unroll
    for (int j = 0; j < VQ_DIM / 4; ++j) {
        float4 v = xp[j];
        xr[4 * j] = v.x; xr[4 * j + 1] = v.y; xr[4 * j + 2] = v.z; xr[4 * j + 3] = v.w;
    }
    float best = __builtin_inff();
    int bidx = 0;
    for (int c = 0; c < VQ_K; ++c) {
        const float4* ep = (const float4*)(embed + c * VQ_DIM);
        float a0 = 0, a1 = 0, a2 = 0, a3 = 0;
#pragma unroll
        for (int j = 0; j < VQ_DIM / 4; ++j) {
            float4 v = ep[j];
            a0 = fmaf(xr[4 * j], v.x, a0);
            a1 = fmaf(xr[4 * j + 1], v.y, a1);
            a2 = fmaf(xr[4 * j + 2], v.z, a2);
            a3 = fmaf(xr[4 * j + 3], v.w, a3);
        }
        float score = fmaf(-2.0f, (a0 + a1) + (a2 + a3), e2s[c]);
        if (score < best) { best = score; bidx = c; }
    }
    const float4* bp = (const float4*)(embed + (size_t)bidx * VQ_DIM);
    float4* op = (float4*)(out + (size_t)row * VQ_DIM);
#pragma unroll
    for (int j = 0; j < VQ_DIM / 4; ++j) op[j] = bp[j];
}

extern "C" void kernel_launch(void* const* d_in, const int* in_sizes, int n_in,
                              void* d_out, int out_size, void* d_ws, size_t ws_size,
                              hipStream_t stream) {
    const float* x = (const float*)d_in[0];
    const float* embed = (const float*)d_in[1];
    float* out = (float*)d_out;
    if (ws_size < WS_NEEDED) {
        hipLaunchKernelGGL(vq_fallback, dim3(VQ_N / 256), dim3(256), 0, stream, x, embed, out);
        return;
    }
    unsigned char* ws = (unsigned char*)d_ws;
    hipLaunchKernelGGL(vq_prep, dim3(68), dim3(256), 0, stream, embed, ws);
    hipLaunchKernelGGL(vq_stage1, dim3(VQ_N / 128), dim3(256), 0, stream, x, embed, ws, out);
}